// Round 1
// baseline (630.477 us; speedup 1.0000x reference)
//
#include <hip/hip_runtime.h>
#include <hip/hip_bf16.h>

#define NNODES 50000
#define NEDGES 800000
#define ETOT   (NEDGES + NNODES)
#define FIN    256
#define HIDS   32
#define HEADS  8
#define NCLS   40
#define NEG    0.2f

// ---------------- GEMM: C[M,N] = A[M,K] @ B[K,N], fp32 ----------------
// BM=128, BN=64, BK=16; 256 threads; each thread 8x4 outputs.
#define BM 128
#define BN 64
#define BK 16

__global__ __launch_bounds__(256) void gemm_tiled(
    const float* __restrict__ A, const float* __restrict__ B, float* __restrict__ C,
    int M, int N, int K) {
  __shared__ float As[BK][BM];   // k-major
  __shared__ float Bs[BK][BN];
  const int tid = threadIdx.x;
  const int tx = tid & 15, ty = tid >> 4;
  const int m0 = blockIdx.x * BM, n0 = blockIdx.y * BN;
  float acc[8][4];
#pragma unroll
  for (int i = 0; i < 8; ++i)
#pragma unroll
    for (int j = 0; j < 4; ++j) acc[i][j] = 0.f;

  for (int k0 = 0; k0 < K; k0 += BK) {
    // A tile: 128 rows x 16 k = 512 float4, 2 per thread, store transposed
#pragma unroll
    for (int l = 0; l < 2; ++l) {
      int idx = tid + l * 256;
      int r = idx & 127, kg = idx >> 7;   // kg in 0..3
      float4 v = make_float4(0.f, 0.f, 0.f, 0.f);
      int gr = m0 + r;
      if (gr < M) v = *reinterpret_cast<const float4*>(A + (size_t)gr * K + k0 + kg * 4);
      As[kg * 4 + 0][r] = v.x;
      As[kg * 4 + 1][r] = v.y;
      As[kg * 4 + 2][r] = v.z;
      As[kg * 4 + 3][r] = v.w;
    }
    // B tile: 16 k x 64 cols = 256 float4, 1 per thread
    {
      int k = tid >> 4, cg = tid & 15;
      int gc = n0 + cg * 4;
      float4 v = make_float4(0.f, 0.f, 0.f, 0.f);
      if (gc + 3 < N) v = *reinterpret_cast<const float4*>(B + (size_t)(k0 + k) * N + gc);
      *reinterpret_cast<float4*>(&Bs[k][cg * 4]) = v;
    }
    __syncthreads();
#pragma unroll
    for (int k = 0; k < BK; ++k) {
      float4 a0 = *reinterpret_cast<const float4*>(&As[k][ty * 8]);
      float4 a1 = *reinterpret_cast<const float4*>(&As[k][ty * 8 + 4]);
      float4 b  = *reinterpret_cast<const float4*>(&Bs[k][tx * 4]);
      float av[8] = {a0.x, a0.y, a0.z, a0.w, a1.x, a1.y, a1.z, a1.w};
      float bv[4] = {b.x, b.y, b.z, b.w};
#pragma unroll
      for (int i = 0; i < 8; ++i)
#pragma unroll
        for (int j = 0; j < 4; ++j) acc[i][j] += av[i] * bv[j];
    }
    __syncthreads();
  }
#pragma unroll
  for (int i = 0; i < 8; ++i) {
    int gr = m0 + ty * 8 + i;
    if (gr >= M) continue;
    int gc = n0 + tx * 4;
    if (gc + 3 < N) {
      float4 o = make_float4(acc[i][0], acc[i][1], acc[i][2], acc[i][3]);
      *reinterpret_cast<float4*>(C + (size_t)gr * N + gc) = o;
    }
  }
}

// ---------------- alpha1: per node, per head dot(xw, a_src/a_dst) ----------------
__global__ __launch_bounds__(256) void alpha1_k(
    const float* __restrict__ xw1, const float* __restrict__ a1src,
    const float* __restrict__ a1dst, float* __restrict__ os, float* __restrict__ od, int n) {
  int wid = (blockIdx.x * 256 + threadIdx.x) >> 6;
  if (wid >= n) return;
  int lane = threadIdx.x & 63;
  float4 xv = *reinterpret_cast<const float4*>(xw1 + (size_t)wid * 256 + lane * 4);
  float4 as = *reinterpret_cast<const float4*>(a1src + lane * 4);
  float4 ad = *reinterpret_cast<const float4*>(a1dst + lane * 4);
  float s = xv.x * as.x + xv.y * as.y + xv.z * as.z + xv.w * as.w;
  float d = xv.x * ad.x + xv.y * ad.y + xv.z * ad.z + xv.w * ad.w;
#pragma unroll
  for (int off = 1; off < 8; off <<= 1) {
    s += __shfl_xor(s, off, 64);
    d += __shfl_xor(d, off, 64);
  }
  if ((lane & 7) == 0) {
    os[(size_t)wid * 8 + (lane >> 3)] = s;
    od[(size_t)wid * 8 + (lane >> 3)] = d;
  }
}

// ---------------- CSR build ----------------
__global__ __launch_bounds__(256) void hist_k(const int* __restrict__ dstA, int* __restrict__ cnt) {
  int e = blockIdx.x * 256 + threadIdx.x;
  if (e >= ETOT) return;
  int d = (e < NEDGES) ? dstA[e] : (e - NEDGES);
  atomicAdd(&cnt[d], 1);
}

__global__ __launch_bounds__(1024) void scan_k(const int* __restrict__ deg, int* __restrict__ row_ptr, int n) {
  __shared__ int partial[1024];
  int tid = threadIdx.x;
  const int CH = (n + 1023) / 1024;
  int base = tid * CH;
  int s = 0;
  for (int i = 0; i < CH; ++i) {
    int idx = base + i;
    if (idx < n) s += deg[idx];
  }
  partial[tid] = s;
  __syncthreads();
  for (int off = 1; off < 1024; off <<= 1) {
    int v = 0;
    if (tid >= off) v = partial[tid - off];
    __syncthreads();
    if (tid >= off) partial[tid] += v;
    __syncthreads();
  }
  int run = (tid > 0) ? partial[tid - 1] : 0;
  for (int i = 0; i < CH; ++i) {
    int idx = base + i;
    if (idx < n) {
      row_ptr[idx] = run;
      run += deg[idx];
    }
  }
  if (tid == 1023) row_ptr[n] = partial[1023];
}

__global__ __launch_bounds__(256) void scatter_k(const int* __restrict__ srcA, const int* __restrict__ dstA,
                                                 const int* __restrict__ row_ptr, int* __restrict__ cnt,
                                                 int* __restrict__ col) {
  int e = blockIdx.x * 256 + threadIdx.x;
  if (e >= ETOT) return;
  int s, d;
  if (e < NEDGES) { s = srcA[e]; d = dstA[e]; }
  else { s = d = e - NEDGES; }
  int pos = row_ptr[d] + atomicAdd(&cnt[d], 1);
  col[pos] = s;
}

// ---------------- layer-1 aggregate: wave per dst node ----------------
__global__ __launch_bounds__(256) void agg1_k(
    const float* __restrict__ xw1, const float* __restrict__ a1s, const float* __restrict__ a1d,
    const int* __restrict__ row_ptr, const int* __restrict__ col,
    const float* __restrict__ b1, float* __restrict__ hout, int n) {
  int wid = (blockIdx.x * 256 + threadIdx.x) >> 6;
  if (wid >= n) return;
  int lane = threadIdx.x & 63;
  int hh = lane >> 3;
  int beg = row_ptr[wid], end = row_ptr[wid + 1];
  float ad = a1d[(size_t)wid * 8 + hh];
  float m = -1e30f;
  for (int i = beg; i < end; ++i) {
    int s = col[i];
    float e = a1s[(size_t)s * 8 + hh] + ad;
    e = (e >= 0.f) ? e : NEG * e;
    m = fmaxf(m, e);
  }
  float denom = 0.f;
  float ax = 0.f, ay = 0.f, az = 0.f, aw = 0.f;
  for (int i = beg; i < end; ++i) {
    int s = col[i];
    float e = a1s[(size_t)s * 8 + hh] + ad;
    e = (e >= 0.f) ? e : NEG * e;
    float w = __expf(e - m);
    denom += w;
    float4 xv = *reinterpret_cast<const float4*>(xw1 + (size_t)s * 256 + lane * 4);
    ax += w * xv.x; ay += w * xv.y; az += w * xv.z; aw += w * xv.w;
  }
  float inv = 1.f / denom;
  float4 bv = *reinterpret_cast<const float4*>(b1 + lane * 4);
  float ox = ax * inv + bv.x;
  float oy = ay * inv + bv.y;
  float oz = az * inv + bv.z;
  float ow = aw * inv + bv.w;
  // ELU
  ox = (ox > 0.f) ? ox : expm1f(ox);
  oy = (oy > 0.f) ? oy : expm1f(oy);
  oz = (oz > 0.f) ? oz : expm1f(oz);
  ow = (ow > 0.f) ? ow : expm1f(ow);
  float4 o = make_float4(ox, oy, oz, ow);
  *reinterpret_cast<float4*>(hout + (size_t)wid * 256 + lane * 4) = o;
}

// ---------------- alpha2: thread per node ----------------
__global__ __launch_bounds__(256) void alpha2_k(
    const float* __restrict__ xw2, const float* __restrict__ a2s_in, const float* __restrict__ a2d_in,
    float* __restrict__ os, float* __restrict__ od, int n) {
  int v = blockIdx.x * 256 + threadIdx.x;
  if (v >= n) return;
  float s = 0.f, d = 0.f;
#pragma unroll
  for (int j = 0; j < 10; ++j) {
    float4 xv = *reinterpret_cast<const float4*>(xw2 + (size_t)v * 40 + j * 4);
    float4 as = *reinterpret_cast<const float4*>(a2s_in + j * 4);
    float4 ad = *reinterpret_cast<const float4*>(a2d_in + j * 4);
    s += xv.x * as.x + xv.y * as.y + xv.z * as.z + xv.w * as.w;
    d += xv.x * ad.x + xv.y * ad.y + xv.z * ad.z + xv.w * ad.w;
  }
  os[v] = s;
  od[v] = d;
}

// ---------------- layer-2 aggregate: wave per dst node ----------------
__global__ __launch_bounds__(256) void agg2_k(
    const float* __restrict__ xw2, const float* __restrict__ a2s, const float* __restrict__ a2d,
    const int* __restrict__ row_ptr, const int* __restrict__ col,
    const float* __restrict__ b2, float* __restrict__ out, int n) {
  int wid = (blockIdx.x * 256 + threadIdx.x) >> 6;
  if (wid >= n) return;
  int lane = threadIdx.x & 63;
  int beg = row_ptr[wid], end = row_ptr[wid + 1];
  float ad = a2d[wid];
  float m = -1e30f;
  for (int i = beg; i < end; ++i) {
    float e = a2s[col[i]] + ad;
    e = (e >= 0.f) ? e : NEG * e;
    m = fmaxf(m, e);
  }
  float denom = 0.f, acc = 0.f;
  for (int i = beg; i < end; ++i) {
    int s = col[i];
    float e = a2s[(size_t)s] + ad;
    e = (e >= 0.f) ? e : NEG * e;
    float w = __expf(e - m);
    denom += w;
    if (lane < 40) acc += w * xw2[(size_t)s * 40 + lane];
  }
  if (lane < 40) out[(size_t)wid * 40 + lane] = acc / denom + b2[lane];
}

extern "C" void kernel_launch(void* const* d_in, const int* in_sizes, int n_in,
                              void* d_out, int out_size, void* d_ws, size_t ws_size,
                              hipStream_t stream) {
  const float* x     = (const float*)d_in[0];
  const int*   ei    = (const int*)d_in[1];   // [2, E]: first E = src, next E = dst
  const float* W1    = (const float*)d_in[2];
  const float* a1src = (const float*)d_in[3];
  const float* a1dst = (const float*)d_in[4];
  const float* b1    = (const float*)d_in[5];
  const float* W2    = (const float*)d_in[6];
  const float* a2src = (const float*)d_in[7];
  const float* a2dst = (const float*)d_in[8];
  const float* b2    = (const float*)d_in[9];
  float* out = (float*)d_out;

  const int* srcA = ei;
  const int* dstA = ei + NEDGES;

  float* wsf = (float*)d_ws;
  size_t o = 0;
  float* xw1 = wsf + o; o += (size_t)NNODES * 256;
  float* h   = wsf + o; o += (size_t)NNODES * 256;
  float* a1s = wsf + o; o += (size_t)NNODES * 8;
  float* a1d = wsf + o; o += (size_t)NNODES * 8;
  float* a2s = wsf + o; o += (size_t)NNODES;
  float* a2d = wsf + o; o += (size_t)NNODES;
  float* xw2 = xw1;  // xw1 dead after agg1; reuse for layer-2 features
  int* ip = (int*)(wsf + o);
  int* row_ptr = ip;                 // NNODES+1
  int* cnt     = ip + (NNODES + 1);  // NNODES
  int* col     = cnt + NNODES;       // ETOT

  // 1. zero degree counters
  hipMemsetAsync(cnt, 0, (size_t)NNODES * sizeof(int), stream);

  // 2. GEMM1: xw1 = x @ W1  [N,256]
  {
    dim3 grid((NNODES + BM - 1) / BM, FIN * 1 / BN);  // 391 x 4
    gemm_tiled<<<grid, 256, 0, stream>>>(x, W1, xw1, NNODES, HEADS * HIDS, FIN);
  }

  // 3. alpha1
  alpha1_k<<<(NNODES + 3) / 4, 256, 0, stream>>>(xw1, a1src, a1dst, a1s, a1d, NNODES);

  // 4. CSR build
  hist_k<<<(ETOT + 255) / 256, 256, 0, stream>>>(dstA, cnt);
  scan_k<<<1, 1024, 0, stream>>>(cnt, row_ptr, NNODES);
  hipMemsetAsync(cnt, 0, (size_t)NNODES * sizeof(int), stream);
  scatter_k<<<(ETOT + 255) / 256, 256, 0, stream>>>(srcA, dstA, row_ptr, cnt, col);

  // 5. layer-1 aggregate + bias + ELU -> h
  agg1_k<<<(NNODES + 3) / 4, 256, 0, stream>>>(xw1, a1s, a1d, row_ptr, col, b1, h, NNODES);

  // 6. GEMM2: xw2 = h @ W2  [N,40]
  {
    dim3 grid((NNODES + BM - 1) / BM, 1);
    gemm_tiled<<<grid, 256, 0, stream>>>(h, W2, xw2, NNODES, NCLS, HEADS * HIDS);
  }

  // 7. alpha2
  alpha2_k<<<(NNODES + 255) / 256, 256, 0, stream>>>(xw2, a2src, a2dst, a2s, a2d, NNODES);

  // 8. layer-2 aggregate -> out
  agg2_k<<<(NNODES + 3) / 4, 256, 0, stream>>>(xw2, a2s, a2d, row_ptr, col, b2, out, NNODES);
}

// Round 2
// 507.283 us; speedup vs baseline: 1.2428x; 1.2428x over previous
//
#include <hip/hip_runtime.h>
#include <hip/hip_bf16.h>

#define NNODES 50000
#define NEDGES 800000
#define ETOT   (NEDGES + NNODES)
#define FIN    256
#define HIDS   32
#define HEADS  8
#define NCLS   40
#define NEG    0.2f

// ---------------- GEMM: C[M,N] = A[M,K] @ B[K,N], fp32 ----------------
#define BM 128
#define BN 64
#define BK 16

__global__ __launch_bounds__(256) void gemm_tiled(
    const float* __restrict__ A, const float* __restrict__ B, float* __restrict__ C,
    int M, int N, int K) {
  __shared__ float As[BK][BM];   // k-major
  __shared__ float Bs[BK][BN];
  const int tid = threadIdx.x;
  const int tx = tid & 15, ty = tid >> 4;
  const int m0 = blockIdx.x * BM, n0 = blockIdx.y * BN;
  float acc[8][4];
#pragma unroll
  for (int i = 0; i < 8; ++i)
#pragma unroll
    for (int j = 0; j < 4; ++j) acc[i][j] = 0.f;

  for (int k0 = 0; k0 < K; k0 += BK) {
#pragma unroll
    for (int l = 0; l < 2; ++l) {
      int idx = tid + l * 256;
      int r = idx & 127, kg = idx >> 7;
      float4 v = make_float4(0.f, 0.f, 0.f, 0.f);
      int gr = m0 + r;
      if (gr < M) v = *reinterpret_cast<const float4*>(A + (size_t)gr * K + k0 + kg * 4);
      As[kg * 4 + 0][r] = v.x;
      As[kg * 4 + 1][r] = v.y;
      As[kg * 4 + 2][r] = v.z;
      As[kg * 4 + 3][r] = v.w;
    }
    {
      int k = tid >> 4, cg = tid & 15;
      int gc = n0 + cg * 4;
      float4 v = make_float4(0.f, 0.f, 0.f, 0.f);
      if (gc + 3 < N) v = *reinterpret_cast<const float4*>(B + (size_t)(k0 + k) * N + gc);
      *reinterpret_cast<float4*>(&Bs[k][cg * 4]) = v;
    }
    __syncthreads();
#pragma unroll
    for (int k = 0; k < BK; ++k) {
      float4 a0 = *reinterpret_cast<const float4*>(&As[k][ty * 8]);
      float4 a1 = *reinterpret_cast<const float4*>(&As[k][ty * 8 + 4]);
      float4 b  = *reinterpret_cast<const float4*>(&Bs[k][tx * 4]);
      float av[8] = {a0.x, a0.y, a0.z, a0.w, a1.x, a1.y, a1.z, a1.w};
      float bv[4] = {b.x, b.y, b.z, b.w};
#pragma unroll
      for (int i = 0; i < 8; ++i)
#pragma unroll
        for (int j = 0; j < 4; ++j) acc[i][j] += av[i] * bv[j];
    }
    __syncthreads();
  }
#pragma unroll
  for (int i = 0; i < 8; ++i) {
    int gr = m0 + ty * 8 + i;
    if (gr >= M) continue;
    int gc = n0 + tx * 4;
    if (gc + 3 < N) {
      float4 o = make_float4(acc[i][0], acc[i][1], acc[i][2], acc[i][3]);
      *reinterpret_cast<float4*>(C + (size_t)gr * N + gc) = o;
    }
  }
}

// ---------------- alpha1 ----------------
__global__ __launch_bounds__(256) void alpha1_k(
    const float* __restrict__ xw1, const float* __restrict__ a1src,
    const float* __restrict__ a1dst, float* __restrict__ os, float* __restrict__ od, int n) {
  int wid = (blockIdx.x * 256 + threadIdx.x) >> 6;
  if (wid >= n) return;
  int lane = threadIdx.x & 63;
  float4 xv = *reinterpret_cast<const float4*>(xw1 + (size_t)wid * 256 + lane * 4);
  float4 as = *reinterpret_cast<const float4*>(a1src + lane * 4);
  float4 ad = *reinterpret_cast<const float4*>(a1dst + lane * 4);
  float s = xv.x * as.x + xv.y * as.y + xv.z * as.z + xv.w * as.w;
  float d = xv.x * ad.x + xv.y * ad.y + xv.z * ad.z + xv.w * ad.w;
#pragma unroll
  for (int off = 1; off < 8; off <<= 1) {
    s += __shfl_xor(s, off, 64);
    d += __shfl_xor(d, off, 64);
  }
  if ((lane & 7) == 0) {
    os[(size_t)wid * 8 + (lane >> 3)] = s;
    od[(size_t)wid * 8 + (lane >> 3)] = d;
  }
}

// ---------------- CSR build ----------------
__global__ __launch_bounds__(256) void hist_k(const int* __restrict__ dstA, int* __restrict__ cnt) {
  int e = blockIdx.x * 256 + threadIdx.x;
  if (e >= ETOT) return;
  int d = (e < NEDGES) ? dstA[e] : (e - NEDGES);
  atomicAdd(&cnt[d], 1);
}

__global__ __launch_bounds__(1024) void scan_k(const int* __restrict__ deg, int* __restrict__ row_ptr, int n) {
  __shared__ int partial[1024];
  int tid = threadIdx.x;
  const int CH = (n + 1023) / 1024;
  int base = tid * CH;
  int s = 0;
  for (int i = 0; i < CH; ++i) {
    int idx = base + i;
    if (idx < n) s += deg[idx];
  }
  partial[tid] = s;
  __syncthreads();
  for (int off = 1; off < 1024; off <<= 1) {
    int v = 0;
    if (tid >= off) v = partial[tid - off];
    __syncthreads();
    if (tid >= off) partial[tid] += v;
    __syncthreads();
  }
  int run = (tid > 0) ? partial[tid - 1] : 0;
  for (int i = 0; i < CH; ++i) {
    int idx = base + i;
    if (idx < n) {
      row_ptr[idx] = run;
      run += deg[idx];
    }
  }
  if (tid == 1023) row_ptr[n] = partial[1023];
}

__global__ __launch_bounds__(256) void scatter_k(const int* __restrict__ srcA, const int* __restrict__ dstA,
                                                 const int* __restrict__ row_ptr, int* __restrict__ cnt,
                                                 int* __restrict__ col) {
  int e = blockIdx.x * 256 + threadIdx.x;
  if (e >= ETOT) return;
  int s, d;
  if (e < NEDGES) { s = srcA[e]; d = dstA[e]; }
  else { s = d = e - NEDGES; }
  int pos = row_ptr[d] + atomicAdd(&cnt[d], 1);
  col[pos] = s;
}

// ---------------- layer-1 aggregate (single pass, no max, unrolled x4) ----------------
__global__ __launch_bounds__(256) void agg1_k(
    const float* __restrict__ xw1, const float* __restrict__ a1s, const float* __restrict__ a1d,
    const int* __restrict__ row_ptr, const int* __restrict__ col,
    const float* __restrict__ b1, float* __restrict__ hout, int n) {
  int wid = (blockIdx.x * 256 + threadIdx.x) >> 6;
  if (wid >= n) return;
  int lane = threadIdx.x & 63;
  int hh = lane >> 3;
  int beg = row_ptr[wid], end = row_ptr[wid + 1];
  float ad = a1d[(size_t)wid * 8 + hh];
  float denom = 0.f, ax = 0.f, ay = 0.f, az = 0.f, aw = 0.f;
  int i = beg;
  for (; i + 4 <= end; i += 4) {
    int s0 = col[i], s1 = col[i + 1], s2 = col[i + 2], s3 = col[i + 3];
    float e0 = a1s[(size_t)s0 * 8 + hh] + ad;
    float e1 = a1s[(size_t)s1 * 8 + hh] + ad;
    float e2 = a1s[(size_t)s2 * 8 + hh] + ad;
    float e3 = a1s[(size_t)s3 * 8 + hh] + ad;
    float4 v0 = *reinterpret_cast<const float4*>(xw1 + (size_t)s0 * 256 + lane * 4);
    float4 v1 = *reinterpret_cast<const float4*>(xw1 + (size_t)s1 * 256 + lane * 4);
    float4 v2 = *reinterpret_cast<const float4*>(xw1 + (size_t)s2 * 256 + lane * 4);
    float4 v3 = *reinterpret_cast<const float4*>(xw1 + (size_t)s3 * 256 + lane * 4);
    float w0 = __expf(fmaxf(e0, 0.f) + NEG * fminf(e0, 0.f));
    float w1 = __expf(fmaxf(e1, 0.f) + NEG * fminf(e1, 0.f));
    float w2 = __expf(fmaxf(e2, 0.f) + NEG * fminf(e2, 0.f));
    float w3 = __expf(fmaxf(e3, 0.f) + NEG * fminf(e3, 0.f));
    denom += (w0 + w1) + (w2 + w3);
    ax += w0 * v0.x + w1 * v1.x + w2 * v2.x + w3 * v3.x;
    ay += w0 * v0.y + w1 * v1.y + w2 * v2.y + w3 * v3.y;
    az += w0 * v0.z + w1 * v1.z + w2 * v2.z + w3 * v3.z;
    aw += w0 * v0.w + w1 * v1.w + w2 * v2.w + w3 * v3.w;
  }
  for (; i < end; ++i) {
    int s = col[i];
    float e = a1s[(size_t)s * 8 + hh] + ad;
    float w = __expf(fmaxf(e, 0.f) + NEG * fminf(e, 0.f));
    float4 v = *reinterpret_cast<const float4*>(xw1 + (size_t)s * 256 + lane * 4);
    denom += w;
    ax += w * v.x; ay += w * v.y; az += w * v.z; aw += w * v.w;
  }
  float inv = 1.f / denom;
  float4 bv = *reinterpret_cast<const float4*>(b1 + lane * 4);
  float ox = ax * inv + bv.x;
  float oy = ay * inv + bv.y;
  float oz = az * inv + bv.z;
  float ow = aw * inv + bv.w;
  ox = (ox > 0.f) ? ox : expm1f(ox);
  oy = (oy > 0.f) ? oy : expm1f(oy);
  oz = (oz > 0.f) ? oz : expm1f(oz);
  ow = (ow > 0.f) ? ow : expm1f(ow);
  *reinterpret_cast<float4*>(hout + (size_t)wid * 256 + lane * 4) =
      make_float4(ox, oy, oz, ow);
}

// ---------------- alpha2 ----------------
__global__ __launch_bounds__(256) void alpha2_k(
    const float* __restrict__ xw2, const float* __restrict__ a2s_in, const float* __restrict__ a2d_in,
    float* __restrict__ os, float* __restrict__ od, int n) {
  int v = blockIdx.x * 256 + threadIdx.x;
  if (v >= n) return;
  float s = 0.f, d = 0.f;
#pragma unroll
  for (int j = 0; j < 10; ++j) {
    float4 xv = *reinterpret_cast<const float4*>(xw2 + (size_t)v * 40 + j * 4);
    float4 as = *reinterpret_cast<const float4*>(a2s_in + j * 4);
    float4 ad = *reinterpret_cast<const float4*>(a2d_in + j * 4);
    s += xv.x * as.x + xv.y * as.y + xv.z * as.z + xv.w * as.w;
    d += xv.x * ad.x + xv.y * ad.y + xv.z * ad.z + xv.w * ad.w;
  }
  os[v] = s;
  od[v] = d;
}

// ---------------- layer-2 aggregate (single pass, no max, unrolled x4) ----------------
__global__ __launch_bounds__(256) void agg2_k(
    const float* __restrict__ xw2, const float* __restrict__ a2s, const float* __restrict__ a2d,
    const int* __restrict__ row_ptr, const int* __restrict__ col,
    const float* __restrict__ b2, float* __restrict__ out, int n) {
  int wid = (blockIdx.x * 256 + threadIdx.x) >> 6;
  if (wid >= n) return;
  int lane = threadIdx.x & 63;
  int beg = row_ptr[wid], end = row_ptr[wid + 1];
  float ad = a2d[wid];
  float denom = 0.f, acc = 0.f;
  int i = beg;
  for (; i + 4 <= end; i += 4) {
    int s0 = col[i], s1 = col[i + 1], s2 = col[i + 2], s3 = col[i + 3];
    float e0 = a2s[s0] + ad;
    float e1 = a2s[s1] + ad;
    float e2 = a2s[s2] + ad;
    float e3 = a2s[s3] + ad;
    float w0 = __expf(fmaxf(e0, 0.f) + NEG * fminf(e0, 0.f));
    float w1 = __expf(fmaxf(e1, 0.f) + NEG * fminf(e1, 0.f));
    float w2 = __expf(fmaxf(e2, 0.f) + NEG * fminf(e2, 0.f));
    float w3 = __expf(fmaxf(e3, 0.f) + NEG * fminf(e3, 0.f));
    float x0 = 0.f, x1 = 0.f, x2 = 0.f, x3 = 0.f;
    if (lane < 40) {
      x0 = xw2[(size_t)s0 * 40 + lane];
      x1 = xw2[(size_t)s1 * 40 + lane];
      x2 = xw2[(size_t)s2 * 40 + lane];
      x3 = xw2[(size_t)s3 * 40 + lane];
    }
    denom += (w0 + w1) + (w2 + w3);
    acc += w0 * x0 + w1 * x1 + w2 * x2 + w3 * x3;
  }
  for (; i < end; ++i) {
    int s = col[i];
    float e = a2s[s] + ad;
    float w = __expf(fmaxf(e, 0.f) + NEG * fminf(e, 0.f));
    denom += w;
    if (lane < 40) acc += w * xw2[(size_t)s * 40 + lane];
  }
  if (lane < 40) out[(size_t)wid * 40 + lane] = acc / denom + b2[lane];
}

extern "C" void kernel_launch(void* const* d_in, const int* in_sizes, int n_in,
                              void* d_out, int out_size, void* d_ws, size_t ws_size,
                              hipStream_t stream) {
  const float* x     = (const float*)d_in[0];
  const int*   ei    = (const int*)d_in[1];
  const float* W1    = (const float*)d_in[2];
  const float* a1src = (const float*)d_in[3];
  const float* a1dst = (const float*)d_in[4];
  const float* b1    = (const float*)d_in[5];
  const float* W2    = (const float*)d_in[6];
  const float* a2src = (const float*)d_in[7];
  const float* a2dst = (const float*)d_in[8];
  const float* b2    = (const float*)d_in[9];
  float* out = (float*)d_out;

  const int* srcA = ei;
  const int* dstA = ei + NEDGES;

  float* wsf = (float*)d_ws;
  size_t o = 0;
  float* xw1 = wsf + o; o += (size_t)NNODES * 256;
  float* h   = wsf + o; o += (size_t)NNODES * 256;
  float* a1s = wsf + o; o += (size_t)NNODES * 8;
  float* a1d = wsf + o; o += (size_t)NNODES * 8;
  float* a2s = wsf + o; o += (size_t)NNODES;
  float* a2d = wsf + o; o += (size_t)NNODES;
  float* xw2 = xw1;  // reuse
  int* ip = (int*)(wsf + o);
  int* row_ptr = ip;
  int* cnt     = ip + (NNODES + 1);
  int* col     = cnt + NNODES;

  hipMemsetAsync(cnt, 0, (size_t)NNODES * sizeof(int), stream);

  {
    dim3 grid((NNODES + BM - 1) / BM, (HEADS * HIDS) / BN);
    gemm_tiled<<<grid, 256, 0, stream>>>(x, W1, xw1, NNODES, HEADS * HIDS, FIN);
  }

  alpha1_k<<<(NNODES + 3) / 4, 256, 0, stream>>>(xw1, a1src, a1dst, a1s, a1d, NNODES);

  hist_k<<<(ETOT + 255) / 256, 256, 0, stream>>>(dstA, cnt);
  scan_k<<<1, 1024, 0, stream>>>(cnt, row_ptr, NNODES);
  hipMemsetAsync(cnt, 0, (size_t)NNODES * sizeof(int), stream);
  scatter_k<<<(ETOT + 255) / 256, 256, 0, stream>>>(srcA, dstA, row_ptr, cnt, col);

  agg1_k<<<(NNODES + 3) / 4, 256, 0, stream>>>(xw1, a1s, a1d, row_ptr, col, b1, h, NNODES);

  {
    dim3 grid((NNODES + BM - 1) / BM, 1);
    gemm_tiled<<<grid, 256, 0, stream>>>(h, W2, xw2, NNODES, NCLS, HEADS * HIDS);
  }

  alpha2_k<<<(NNODES + 255) / 256, 256, 0, stream>>>(xw2, a2src, a2dst, a2s, a2d, NNODES);

  agg2_k<<<(NNODES + 3) / 4, 256, 0, stream>>>(xw2, a2s, a2d, row_ptr, col, b2, out, NNODES);
}

// Round 3
// 386.854 us; speedup vs baseline: 1.6298x; 1.3113x over previous
//
#include <hip/hip_runtime.h>
#include <hip/hip_bf16.h>

#define NNODES 50000
#define NPAD   50048          // padded to multiple of 64 for GEMM1 tiles
#define NEDGES 800000
#define ETOT   (NEDGES + NNODES)
#define FIN    256
#define HIDS   32
#define HEADS  8
#define NCLS   40
#define NEG    0.2f

typedef __attribute__((ext_vector_type(8))) short bf16x8;
typedef __attribute__((ext_vector_type(4))) float f32x4;

__device__ __forceinline__ ushort f2bf(float f) {
  unsigned u = __float_as_uint(f);
  unsigned r = (u + 0x7fffu + ((u >> 16) & 1u)) >> 16;   // RNE
  return (ushort)r;
}
__device__ __forceinline__ float bf2f(ushort u) {
  return __uint_as_float(((unsigned)u) << 16);
}

// ---------------- convert x -> bf16 (padded rows zeroed) ----------------
__global__ __launch_bounds__(256) void conv_x(const float* __restrict__ x, ushort* __restrict__ xb) {
  size_t gid = (size_t)blockIdx.x * 256 + threadIdx.x;   // NPAD*32 threads
  int row = (int)(gid >> 5);
  int c0 = ((int)gid & 31) * 8;
  if (row >= NPAD) return;
  bf16x8 o;
  if (row < NNODES) {
    const float4* xp = (const float4*)(x + (size_t)row * 256 + c0);
    float4 a = xp[0], b = xp[1];
    o[0] = (short)f2bf(a.x); o[1] = (short)f2bf(a.y);
    o[2] = (short)f2bf(a.z); o[3] = (short)f2bf(a.w);
    o[4] = (short)f2bf(b.x); o[5] = (short)f2bf(b.y);
    o[6] = (short)f2bf(b.z); o[7] = (short)f2bf(b.w);
  } else {
    o = (bf16x8)0;
  }
  *(bf16x8*)(xb + (size_t)row * 256 + c0) = o;
}

// ---------------- convert W1 [K=256][N=256] -> W1t bf16 [N][K] ----------------
__global__ __launch_bounds__(256) void conv_w1t(const float* __restrict__ W1, ushort* __restrict__ w1t) {
  int k = blockIdx.x, n = threadIdx.x;
  w1t[(size_t)n * 256 + k] = f2bf(W1[(size_t)k * 256 + n]);
}

// ---------------- GEMM1: xw1b[NPAD,256](bf16) = xb @ W1t^T via MFMA ----------------
// BM=64, full N=256, BK=32; 4 waves; wave w: all 4 m-tiles x n-tiles [w*4, w*4+4)
__global__ __launch_bounds__(256) void gemm1_mfma(
    const ushort* __restrict__ xb, const ushort* __restrict__ w1t, ushort* __restrict__ xw1b) {
  __shared__ ushort As[64 * 40];    // [row][k], pitch 40 halfs (80B)
  __shared__ ushort Bs[256 * 40];   // [n][k],  pitch 40
  const int tid = threadIdx.x;
  const int m0 = blockIdx.x * 64;
  const int w = tid >> 6, l = tid & 63, lr = l & 15, lq = l >> 4;
  f32x4 acc[4][4];
#pragma unroll
  for (int i = 0; i < 4; ++i)
#pragma unroll
    for (int j = 0; j < 4; ++j) acc[i][j] = (f32x4)0.f;

  for (int k0 = 0; k0 < 256; k0 += 32) {
    {
      int row = tid >> 2, kg = (tid & 3) * 8;
      *(bf16x8*)&As[row * 40 + kg] = *(const bf16x8*)(xb + (size_t)(m0 + row) * 256 + k0 + kg);
    }
#pragma unroll
    for (int p = 0; p < 4; ++p) {
      int idx = tid + p * 256;
      int n = idx >> 2, kg = (idx & 3) * 8;
      *(bf16x8*)&Bs[n * 40 + kg] = *(const bf16x8*)(w1t + (size_t)n * 256 + k0 + kg);
    }
    __syncthreads();
    bf16x8 af[4], bf[4];
#pragma unroll
    for (int mt = 0; mt < 4; ++mt)
      af[mt] = *(const bf16x8*)&As[(mt * 16 + lr) * 40 + lq * 8];
#pragma unroll
    for (int nt = 0; nt < 4; ++nt)
      bf[nt] = *(const bf16x8*)&Bs[((w * 4 + nt) * 16 + lr) * 40 + lq * 8];
#pragma unroll
    for (int mt = 0; mt < 4; ++mt)
#pragma unroll
      for (int nt = 0; nt < 4; ++nt)
        acc[mt][nt] = __builtin_amdgcn_mfma_f32_16x16x32_bf16(af[mt], bf[nt], acc[mt][nt], 0, 0, 0);
    __syncthreads();
  }
#pragma unroll
  for (int mt = 0; mt < 4; ++mt)
#pragma unroll
    for (int nt = 0; nt < 4; ++nt)
#pragma unroll
      for (int r = 0; r < 4; ++r) {
        int row = m0 + mt * 16 + lq * 4 + r;
        int col = (w * 4 + nt) * 16 + lr;
        xw1b[(size_t)row * 256 + col] = f2bf(acc[mt][nt][r]);
      }
}

// ---------------- fp32 GEMM (layer 2): C[M,N] = A[M,K] @ B[K,N] ----------------
#define BM 128
#define BN 64
#define BK 16

__global__ __launch_bounds__(256) void gemm_tiled(
    const float* __restrict__ A, const float* __restrict__ B, float* __restrict__ C,
    int M, int N, int K) {
  __shared__ float As[BK][BM];
  __shared__ float Bs[BK][BN];
  const int tid = threadIdx.x;
  const int tx = tid & 15, ty = tid >> 4;
  const int m0 = blockIdx.x * BM, n0 = blockIdx.y * BN;
  float acc[8][4];
#pragma unroll
  for (int i = 0; i < 8; ++i)
#pragma unroll
    for (int j = 0; j < 4; ++j) acc[i][j] = 0.f;

  for (int k0 = 0; k0 < K; k0 += BK) {
#pragma unroll
    for (int l = 0; l < 2; ++l) {
      int idx = tid + l * 256;
      int r = idx & 127, kg = idx >> 7;
      float4 v = make_float4(0.f, 0.f, 0.f, 0.f);
      int gr = m0 + r;
      if (gr < M) v = *reinterpret_cast<const float4*>(A + (size_t)gr * K + k0 + kg * 4);
      As[kg * 4 + 0][r] = v.x;
      As[kg * 4 + 1][r] = v.y;
      As[kg * 4 + 2][r] = v.z;
      As[kg * 4 + 3][r] = v.w;
    }
    {
      int k = tid >> 4, cg = tid & 15;
      int gc = n0 + cg * 4;
      float4 v = make_float4(0.f, 0.f, 0.f, 0.f);
      if (gc + 3 < N) v = *reinterpret_cast<const float4*>(B + (size_t)(k0 + k) * N + gc);
      *reinterpret_cast<float4*>(&Bs[k][cg * 4]) = v;
    }
    __syncthreads();
#pragma unroll
    for (int k = 0; k < BK; ++k) {
      float4 a0 = *reinterpret_cast<const float4*>(&As[k][ty * 8]);
      float4 a1 = *reinterpret_cast<const float4*>(&As[k][ty * 8 + 4]);
      float4 b  = *reinterpret_cast<const float4*>(&Bs[k][tx * 4]);
      float av[8] = {a0.x, a0.y, a0.z, a0.w, a1.x, a1.y, a1.z, a1.w};
      float bv[4] = {b.x, b.y, b.z, b.w};
#pragma unroll
      for (int i = 0; i < 8; ++i)
#pragma unroll
        for (int j = 0; j < 4; ++j) acc[i][j] += av[i] * bv[j];
    }
    __syncthreads();
  }
#pragma unroll
  for (int i = 0; i < 8; ++i) {
    int gr = m0 + ty * 8 + i;
    if (gr >= M) continue;
    int gc = n0 + tx * 4;
    if (gc + 3 < N) {
      float4 o = make_float4(acc[i][0], acc[i][1], acc[i][2], acc[i][3]);
      *reinterpret_cast<float4*>(C + (size_t)gr * N + gc) = o;
    }
  }
}

// ---------------- alpha1 (reads bf16 xw1) ----------------
__global__ __launch_bounds__(256) void alpha1_k(
    const ushort* __restrict__ xw1b, const float* __restrict__ a1src,
    const float* __restrict__ a1dst, float* __restrict__ os, float* __restrict__ od, int n) {
  int wid = (blockIdx.x * 256 + threadIdx.x) >> 6;
  if (wid >= n) return;
  int lane = threadIdx.x & 63;
  ushort4 u = *(const ushort4*)(xw1b + (size_t)wid * 256 + lane * 4);
  float4 xv = make_float4(bf2f(u.x), bf2f(u.y), bf2f(u.z), bf2f(u.w));
  float4 as = *reinterpret_cast<const float4*>(a1src + lane * 4);
  float4 ad = *reinterpret_cast<const float4*>(a1dst + lane * 4);
  float s = xv.x * as.x + xv.y * as.y + xv.z * as.z + xv.w * as.w;
  float d = xv.x * ad.x + xv.y * ad.y + xv.z * ad.z + xv.w * ad.w;
#pragma unroll
  for (int off = 1; off < 8; off <<= 1) {
    s += __shfl_xor(s, off, 64);
    d += __shfl_xor(d, off, 64);
  }
  if ((lane & 7) == 0) {
    os[(size_t)wid * 8 + (lane >> 3)] = s;
    od[(size_t)wid * 8 + (lane >> 3)] = d;
  }
}

// ---------------- CSR build ----------------
__global__ __launch_bounds__(256) void hist_k(const int* __restrict__ dstA, int* __restrict__ cnt) {
  int e = blockIdx.x * 256 + threadIdx.x;
  if (e >= ETOT) return;
  int d = (e < NEDGES) ? dstA[e] : (e - NEDGES);
  atomicAdd(&cnt[d], 1);
}

__global__ __launch_bounds__(1024) void scan_k(const int* __restrict__ deg, int* __restrict__ row_ptr, int n) {
  __shared__ int partial[1024];
  int tid = threadIdx.x;
  const int CH = (n + 1023) / 1024;
  int base = tid * CH;
  int s = 0;
  for (int i = 0; i < CH; ++i) {
    int idx = base + i;
    if (idx < n) s += deg[idx];
  }
  partial[tid] = s;
  __syncthreads();
  for (int off = 1; off < 1024; off <<= 1) {
    int v = 0;
    if (tid >= off) v = partial[tid - off];
    __syncthreads();
    if (tid >= off) partial[tid] += v;
    __syncthreads();
  }
  int run = (tid > 0) ? partial[tid - 1] : 0;
  for (int i = 0; i < CH; ++i) {
    int idx = base + i;
    if (idx < n) {
      row_ptr[idx] = run;
      run += deg[idx];
    }
  }
  if (tid == 1023) row_ptr[n] = partial[1023];
}

__global__ __launch_bounds__(256) void scatter_k(const int* __restrict__ srcA, const int* __restrict__ dstA,
                                                 const int* __restrict__ row_ptr, int* __restrict__ cnt,
                                                 int* __restrict__ col) {
  int e = blockIdx.x * 256 + threadIdx.x;
  if (e >= ETOT) return;
  int s, d;
  if (e < NEDGES) { s = srcA[e]; d = dstA[e]; }
  else { s = d = e - NEDGES; }
  int pos = row_ptr[d] + atomicAdd(&cnt[d], 1);
  col[pos] = s;
}

// ---------------- layer-1 aggregate: bf16 gather, single pass ----------------
__global__ __launch_bounds__(256) void agg1_k(
    const ushort* __restrict__ xw1b, const float* __restrict__ a1s, const float* __restrict__ a1d,
    const int* __restrict__ row_ptr, const int* __restrict__ col,
    const float* __restrict__ b1, float* __restrict__ hout, int n) {
  int wid = (blockIdx.x * 256 + threadIdx.x) >> 6;
  if (wid >= n) return;
  int lane = threadIdx.x & 63;
  int hh = lane >> 3;
  int beg = row_ptr[wid], end = row_ptr[wid + 1];
  float ad = a1d[(size_t)wid * 8 + hh];
  float denom = 0.f, ax = 0.f, ay = 0.f, az = 0.f, aw = 0.f;
  int i = beg;
  for (; i + 4 <= end; i += 4) {
    int s0 = col[i], s1 = col[i + 1], s2 = col[i + 2], s3 = col[i + 3];
    float e0 = a1s[(size_t)s0 * 8 + hh] + ad;
    float e1 = a1s[(size_t)s1 * 8 + hh] + ad;
    float e2 = a1s[(size_t)s2 * 8 + hh] + ad;
    float e3 = a1s[(size_t)s3 * 8 + hh] + ad;
    ushort4 u0 = *(const ushort4*)(xw1b + (size_t)s0 * 256 + lane * 4);
    ushort4 u1 = *(const ushort4*)(xw1b + (size_t)s1 * 256 + lane * 4);
    ushort4 u2 = *(const ushort4*)(xw1b + (size_t)s2 * 256 + lane * 4);
    ushort4 u3 = *(const ushort4*)(xw1b + (size_t)s3 * 256 + lane * 4);
    float w0 = __expf(fmaxf(e0, 0.f) + NEG * fminf(e0, 0.f));
    float w1 = __expf(fmaxf(e1, 0.f) + NEG * fminf(e1, 0.f));
    float w2 = __expf(fmaxf(e2, 0.f) + NEG * fminf(e2, 0.f));
    float w3 = __expf(fmaxf(e3, 0.f) + NEG * fminf(e3, 0.f));
    denom += (w0 + w1) + (w2 + w3);
    ax += w0 * bf2f(u0.x) + w1 * bf2f(u1.x) + w2 * bf2f(u2.x) + w3 * bf2f(u3.x);
    ay += w0 * bf2f(u0.y) + w1 * bf2f(u1.y) + w2 * bf2f(u2.y) + w3 * bf2f(u3.y);
    az += w0 * bf2f(u0.z) + w1 * bf2f(u1.z) + w2 * bf2f(u2.z) + w3 * bf2f(u3.z);
    aw += w0 * bf2f(u0.w) + w1 * bf2f(u1.w) + w2 * bf2f(u2.w) + w3 * bf2f(u3.w);
  }
  for (; i < end; ++i) {
    int s = col[i];
    float e = a1s[(size_t)s * 8 + hh] + ad;
    float w = __expf(fmaxf(e, 0.f) + NEG * fminf(e, 0.f));
    ushort4 u = *(const ushort4*)(xw1b + (size_t)s * 256 + lane * 4);
    denom += w;
    ax += w * bf2f(u.x); ay += w * bf2f(u.y); az += w * bf2f(u.z); aw += w * bf2f(u.w);
  }
  float inv = 1.f / denom;
  float4 bv = *reinterpret_cast<const float4*>(b1 + lane * 4);
  float ox = ax * inv + bv.x;
  float oy = ay * inv + bv.y;
  float oz = az * inv + bv.z;
  float ow = aw * inv + bv.w;
  ox = (ox > 0.f) ? ox : expm1f(ox);
  oy = (oy > 0.f) ? oy : expm1f(oy);
  oz = (oz > 0.f) ? oz : expm1f(oz);
  ow = (ow > 0.f) ? ow : expm1f(ow);
  *reinterpret_cast<float4*>(hout + (size_t)wid * 256 + lane * 4) =
      make_float4(ox, oy, oz, ow);
}

// ---------------- alpha2 ----------------
__global__ __launch_bounds__(256) void alpha2_k(
    const float* __restrict__ xw2, const float* __restrict__ a2s_in, const float* __restrict__ a2d_in,
    float* __restrict__ os, float* __restrict__ od, int n) {
  int v = blockIdx.x * 256 + threadIdx.x;
  if (v >= n) return;
  float s = 0.f, d = 0.f;
#pragma unroll
  for (int j = 0; j < 10; ++j) {
    float4 xv = *reinterpret_cast<const float4*>(xw2 + (size_t)v * 40 + j * 4);
    float4 as = *reinterpret_cast<const float4*>(a2s_in + j * 4);
    float4 ad = *reinterpret_cast<const float4*>(a2d_in + j * 4);
    s += xv.x * as.x + xv.y * as.y + xv.z * as.z + xv.w * as.w;
    d += xv.x * ad.x + xv.y * ad.y + xv.z * ad.z + xv.w * ad.w;
  }
  os[v] = s;
  od[v] = d;
}

// ---------------- layer-2 aggregate ----------------
__global__ __launch_bounds__(256) void agg2_k(
    const float* __restrict__ xw2, const float* __restrict__ a2s, const float* __restrict__ a2d,
    const int* __restrict__ row_ptr, const int* __restrict__ col,
    const float* __restrict__ b2, float* __restrict__ out, int n) {
  int wid = (blockIdx.x * 256 + threadIdx.x) >> 6;
  if (wid >= n) return;
  int lane = threadIdx.x & 63;
  int beg = row_ptr[wid], end = row_ptr[wid + 1];
  float ad = a2d[wid];
  float denom = 0.f, acc = 0.f;
  int i = beg;
  for (; i + 4 <= end; i += 4) {
    int s0 = col[i], s1 = col[i + 1], s2 = col[i + 2], s3 = col[i + 3];
    float e0 = a2s[s0] + ad;
    float e1 = a2s[s1] + ad;
    float e2 = a2s[s2] + ad;
    float e3 = a2s[s3] + ad;
    float w0 = __expf(fmaxf(e0, 0.f) + NEG * fminf(e0, 0.f));
    float w1 = __expf(fmaxf(e1, 0.f) + NEG * fminf(e1, 0.f));
    float w2 = __expf(fmaxf(e2, 0.f) + NEG * fminf(e2, 0.f));
    float w3 = __expf(fmaxf(e3, 0.f) + NEG * fminf(e3, 0.f));
    float x0 = 0.f, x1 = 0.f, x2 = 0.f, x3 = 0.f;
    if (lane < 40) {
      x0 = xw2[(size_t)s0 * 40 + lane];
      x1 = xw2[(size_t)s1 * 40 + lane];
      x2 = xw2[(size_t)s2 * 40 + lane];
      x3 = xw2[(size_t)s3 * 40 + lane];
    }
    denom += (w0 + w1) + (w2 + w3);
    acc += w0 * x0 + w1 * x1 + w2 * x2 + w3 * x3;
  }
  for (; i < end; ++i) {
    int s = col[i];
    float e = a2s[s] + ad;
    float w = __expf(fmaxf(e, 0.f) + NEG * fminf(e, 0.f));
    denom += w;
    if (lane < 40) acc += w * xw2[(size_t)s * 40 + lane];
  }
  if (lane < 40) out[(size_t)wid * 40 + lane] = acc / denom + b2[lane];
}

extern "C" void kernel_launch(void* const* d_in, const int* in_sizes, int n_in,
                              void* d_out, int out_size, void* d_ws, size_t ws_size,
                              hipStream_t stream) {
  const float* x     = (const float*)d_in[0];
  const int*   ei    = (const int*)d_in[1];
  const float* W1    = (const float*)d_in[2];
  const float* a1src = (const float*)d_in[3];
  const float* a1dst = (const float*)d_in[4];
  const float* b1    = (const float*)d_in[5];
  const float* W2    = (const float*)d_in[6];
  const float* a2src = (const float*)d_in[7];
  const float* a2dst = (const float*)d_in[8];
  const float* b2    = (const float*)d_in[9];
  float* out = (float*)d_out;

  const int* srcA = ei;
  const int* dstA = ei + NEDGES;

  // workspace layout
  ushort* xb   = (ushort*)d_ws;                       // NPAD*256 bf16
  ushort* w1t  = xb + (size_t)NPAD * 256;             // 256*256 bf16
  ushort* xw1b = w1t + 65536;                         // NPAD*256 bf16
  float*  h    = (float*)(xw1b + (size_t)NPAD * 256); // NNODES*256 f32
  float*  a1s  = h + (size_t)NNODES * 256;            // NNODES*8
  float*  a1d  = a1s + (size_t)NNODES * 8;            // NNODES*8
  int* ip      = (int*)(a1d + (size_t)NNODES * 8);
  int* row_ptr = ip;                                  // NNODES+1
  int* cnt     = ip + (NNODES + 1);                   // NNODES
  int* col     = cnt + NNODES;                        // ETOT
  // layer-2 scratch aliases xb (dead after gemm1)
  float* xw2 = (float*)xb;                            // NNODES*40
  float* a2s = xw2 + (size_t)NNODES * 40;
  float* a2d = a2s + NNODES;

  hipMemsetAsync(cnt, 0, (size_t)NNODES * sizeof(int), stream);

  conv_x<<<(NPAD * 32) / 256, 256, 0, stream>>>(x, xb);
  conv_w1t<<<256, 256, 0, stream>>>(W1, w1t);
  gemm1_mfma<<<NPAD / 64, 256, 0, stream>>>(xb, w1t, xw1b);

  alpha1_k<<<(NNODES + 3) / 4, 256, 0, stream>>>(xw1b, a1src, a1dst, a1s, a1d, NNODES);

  hist_k<<<(ETOT + 255) / 256, 256, 0, stream>>>(dstA, cnt);
  scan_k<<<1, 1024, 0, stream>>>(cnt, row_ptr, NNODES);
  hipMemsetAsync(cnt, 0, (size_t)NNODES * sizeof(int), stream);
  scatter_k<<<(ETOT + 255) / 256, 256, 0, stream>>>(srcA, dstA, row_ptr, cnt, col);

  agg1_k<<<(NNODES + 3) / 4, 256, 0, stream>>>(xw1b, a1s, a1d, row_ptr, col, b1, h, NNODES);

  {
    dim3 grid((NNODES + BM - 1) / BM, 1);
    gemm_tiled<<<grid, 256, 0, stream>>>(h, W2, xw2, NNODES, NCLS, HEADS * HIDS);
  }

  alpha2_k<<<(NNODES + 255) / 256, 256, 0, stream>>>(xw2, a2src, a2dst, a2s, a2d, NNODES);

  agg2_k<<<(NNODES + 3) / 4, 256, 0, stream>>>(xw2, a2s, a2d, row_ptr, col, b2, out, NNODES);
}

// Round 4
// 302.816 us; speedup vs baseline: 2.0820x; 1.2775x over previous
//
#include <hip/hip_runtime.h>
#include <hip/hip_bf16.h>

#define NNODES 50000
#define NPAD   50048          // padded to multiple of 64 for GEMM1 tiles
#define NEDGES 800000
#define ETOT   (NEDGES + NNODES)
#define FIN    256
#define HIDS   32
#define HEADS  8
#define NCLS   40
#define NEG    0.2f

#define SCAN_B 256
#define NSCB   ((NNODES + SCAN_B - 1) / SCAN_B)   // 196

typedef __attribute__((ext_vector_type(8))) short bf16x8;
typedef __attribute__((ext_vector_type(4))) float f32x4;

__device__ __forceinline__ ushort f2bf(float f) {
  unsigned u = __float_as_uint(f);
  unsigned r = (u + 0x7fffu + ((u >> 16) & 1u)) >> 16;   // RNE
  return (ushort)r;
}
__device__ __forceinline__ float bf2f(ushort u) {
  return __uint_as_float(((unsigned)u) << 16);
}

// ---------------- convert x -> bf16 (padded rows zeroed) ----------------
__global__ __launch_bounds__(256) void conv_x(const float* __restrict__ x, ushort* __restrict__ xb) {
  size_t gid = (size_t)blockIdx.x * 256 + threadIdx.x;   // NPAD*32 threads
  int row = (int)(gid >> 5);
  int c0 = ((int)gid & 31) * 8;
  if (row >= NPAD) return;
  bf16x8 o;
  if (row < NNODES) {
    const float4* xp = (const float4*)(x + (size_t)row * 256 + c0);
    float4 a = xp[0], b = xp[1];
    o[0] = (short)f2bf(a.x); o[1] = (short)f2bf(a.y);
    o[2] = (short)f2bf(a.z); o[3] = (short)f2bf(a.w);
    o[4] = (short)f2bf(b.x); o[5] = (short)f2bf(b.y);
    o[6] = (short)f2bf(b.z); o[7] = (short)f2bf(b.w);
  } else {
    o = (bf16x8)0;
  }
  *(bf16x8*)(xb + (size_t)row * 256 + c0) = o;
}

// ---------------- convert W1 [K=256][N=256] -> W1t bf16 [N][K] ----------------
__global__ __launch_bounds__(256) void conv_w1t(const float* __restrict__ W1, ushort* __restrict__ w1t) {
  int k = blockIdx.x, n = threadIdx.x;
  w1t[(size_t)n * 256 + k] = f2bf(W1[(size_t)k * 256 + n]);
}

// ---------------- GEMM1: xw1b[NPAD,256](bf16) = xb @ W1t^T via MFMA ----------------
__global__ __launch_bounds__(256) void gemm1_mfma(
    const ushort* __restrict__ xb, const ushort* __restrict__ w1t, ushort* __restrict__ xw1b) {
  __shared__ ushort As[64 * 40];    // [row][k], pitch 40 halfs (80B)
  __shared__ ushort Bs[256 * 40];   // [n][k],  pitch 40
  const int tid = threadIdx.x;
  const int m0 = blockIdx.x * 64;
  const int w = tid >> 6, l = tid & 63, lr = l & 15, lq = l >> 4;
  f32x4 acc[4][4];
#pragma unroll
  for (int i = 0; i < 4; ++i)
#pragma unroll
    for (int j = 0; j < 4; ++j) acc[i][j] = (f32x4)0.f;

  for (int k0 = 0; k0 < 256; k0 += 32) {
    {
      int row = tid >> 2, kg = (tid & 3) * 8;
      *(bf16x8*)&As[row * 40 + kg] = *(const bf16x8*)(xb + (size_t)(m0 + row) * 256 + k0 + kg);
    }
#pragma unroll
    for (int p = 0; p < 4; ++p) {
      int idx = tid + p * 256;
      int n = idx >> 2, kg = (idx & 3) * 8;
      *(bf16x8*)&Bs[n * 40 + kg] = *(const bf16x8*)(w1t + (size_t)n * 256 + k0 + kg);
    }
    __syncthreads();
    bf16x8 af[4], bf[4];
#pragma unroll
    for (int mt = 0; mt < 4; ++mt)
      af[mt] = *(const bf16x8*)&As[(mt * 16 + lr) * 40 + lq * 8];
#pragma unroll
    for (int nt = 0; nt < 4; ++nt)
      bf[nt] = *(const bf16x8*)&Bs[((w * 4 + nt) * 16 + lr) * 40 + lq * 8];
#pragma unroll
    for (int mt = 0; mt < 4; ++mt)
#pragma unroll
      for (int nt = 0; nt < 4; ++nt)
        acc[mt][nt] = __builtin_amdgcn_mfma_f32_16x16x32_bf16(af[mt], bf[nt], acc[mt][nt], 0, 0, 0);
    __syncthreads();
  }
#pragma unroll
  for (int mt = 0; mt < 4; ++mt)
#pragma unroll
    for (int nt = 0; nt < 4; ++nt)
#pragma unroll
      for (int r = 0; r < 4; ++r) {
        int row = m0 + mt * 16 + lq * 4 + r;
        int col = (w * 4 + nt) * 16 + lr;
        xw1b[(size_t)row * 256 + col] = f2bf(acc[mt][nt][r]);
      }
}

// ---------------- fp32 GEMM (layer 2): C[M,N] = A[M,K] @ B[K,N] ----------------
#define BM 128
#define BN 64
#define BK 16

__global__ __launch_bounds__(256) void gemm_tiled(
    const float* __restrict__ A, const float* __restrict__ B, float* __restrict__ C,
    int M, int N, int K) {
  __shared__ float As[BK][BM];
  __shared__ float Bs[BK][BN];
  const int tid = threadIdx.x;
  const int tx = tid & 15, ty = tid >> 4;
  const int m0 = blockIdx.x * BM, n0 = blockIdx.y * BN;
  float acc[8][4];
#pragma unroll
  for (int i = 0; i < 8; ++i)
#pragma unroll
    for (int j = 0; j < 4; ++j) acc[i][j] = 0.f;

  for (int k0 = 0; k0 < K; k0 += BK) {
#pragma unroll
    for (int l = 0; l < 2; ++l) {
      int idx = tid + l * 256;
      int r = idx & 127, kg = idx >> 7;
      float4 v = make_float4(0.f, 0.f, 0.f, 0.f);
      int gr = m0 + r;
      if (gr < M) v = *reinterpret_cast<const float4*>(A + (size_t)gr * K + k0 + kg * 4);
      As[kg * 4 + 0][r] = v.x;
      As[kg * 4 + 1][r] = v.y;
      As[kg * 4 + 2][r] = v.z;
      As[kg * 4 + 3][r] = v.w;
    }
    {
      int k = tid >> 4, cg = tid & 15;
      int gc = n0 + cg * 4;
      float4 v = make_float4(0.f, 0.f, 0.f, 0.f);
      if (gc + 3 < N) v = *reinterpret_cast<const float4*>(B + (size_t)(k0 + k) * N + gc);
      *reinterpret_cast<float4*>(&Bs[k][cg * 4]) = v;
    }
    __syncthreads();
#pragma unroll
    for (int k = 0; k < BK; ++k) {
      float4 a0 = *reinterpret_cast<const float4*>(&As[k][ty * 8]);
      float4 a1 = *reinterpret_cast<const float4*>(&As[k][ty * 8 + 4]);
      float4 b  = *reinterpret_cast<const float4*>(&Bs[k][tx * 4]);
      float av[8] = {a0.x, a0.y, a0.z, a0.w, a1.x, a1.y, a1.z, a1.w};
      float bv[4] = {b.x, b.y, b.z, b.w};
#pragma unroll
      for (int i = 0; i < 8; ++i)
#pragma unroll
        for (int j = 0; j < 4; ++j) acc[i][j] += av[i] * bv[j];
    }
    __syncthreads();
  }
#pragma unroll
  for (int i = 0; i < 8; ++i) {
    int gr = m0 + ty * 8 + i;
    if (gr >= M) continue;
    int gc = n0 + tx * 4;
    if (gc + 3 < N) {
      float4 o = make_float4(acc[i][0], acc[i][1], acc[i][2], acc[i][3]);
      *reinterpret_cast<float4*>(C + (size_t)gr * N + gc) = o;
    }
  }
}

// ---------------- alpha1 (reads bf16 xw1) ----------------
__global__ __launch_bounds__(256) void alpha1_k(
    const ushort* __restrict__ xw1b, const float* __restrict__ a1src,
    const float* __restrict__ a1dst, float* __restrict__ os, float* __restrict__ od, int n) {
  int wid = (blockIdx.x * 256 + threadIdx.x) >> 6;
  if (wid >= n) return;
  int lane = threadIdx.x & 63;
  ushort4 u = *(const ushort4*)(xw1b + (size_t)wid * 256 + lane * 4);
  float4 xv = make_float4(bf2f(u.x), bf2f(u.y), bf2f(u.z), bf2f(u.w));
  float4 as = *reinterpret_cast<const float4*>(a1src + lane * 4);
  float4 ad = *reinterpret_cast<const float4*>(a1dst + lane * 4);
  float s = xv.x * as.x + xv.y * as.y + xv.z * as.z + xv.w * as.w;
  float d = xv.x * ad.x + xv.y * ad.y + xv.z * ad.z + xv.w * ad.w;
#pragma unroll
  for (int off = 1; off < 8; off <<= 1) {
    s += __shfl_xor(s, off, 64);
    d += __shfl_xor(d, off, 64);
  }
  if ((lane & 7) == 0) {
    os[(size_t)wid * 8 + (lane >> 3)] = s;
    od[(size_t)wid * 8 + (lane >> 3)] = d;
  }
}

// ---------------- CSR build ----------------
__global__ __launch_bounds__(256) void hist_k(const int* __restrict__ dstA, int* __restrict__ cnt) {
  int e = blockIdx.x * 256 + threadIdx.x;
  if (e >= ETOT) return;
  int d = (e < NEDGES) ? dstA[e] : (e - NEDGES);
  atomicAdd(&cnt[d], 1);
}

// two-level parallel exclusive scan of cnt[NNODES] -> row_ptr[NNODES+1]
__global__ __launch_bounds__(SCAN_B) void scan1_k(const int* __restrict__ deg,
                                                  int* __restrict__ row_ptr,
                                                  int* __restrict__ bsum) {
  __shared__ int sm[SCAN_B];
  int b = blockIdx.x, t = threadIdx.x;
  int idx = b * SCAN_B + t;
  int v = (idx < NNODES) ? deg[idx] : 0;
  sm[t] = v;
  __syncthreads();
#pragma unroll
  for (int off = 1; off < SCAN_B; off <<= 1) {
    int u = (t >= off) ? sm[t - off] : 0;
    __syncthreads();
    sm[t] += u;
    __syncthreads();
  }
  if (idx < NNODES) row_ptr[idx + 1] = sm[t];   // block-local inclusive
  if (t == SCAN_B - 1) bsum[b] = sm[t];
}

__global__ __launch_bounds__(256) void scan2_k(int* __restrict__ bsum) {
  __shared__ int sm[256];
  int t = threadIdx.x;
  sm[t] = (t < NSCB) ? bsum[t] : 0;
  __syncthreads();
#pragma unroll
  for (int off = 1; off < 256; off <<= 1) {
    int u = (t >= off) ? sm[t - off] : 0;
    __syncthreads();
    sm[t] += u;
    __syncthreads();
  }
  if (t < NSCB) bsum[t] = (t > 0) ? sm[t - 1] : 0;   // exclusive block offsets
}

__global__ __launch_bounds__(SCAN_B) void scan3_k(const int* __restrict__ bsum,
                                                  int* __restrict__ row_ptr) {
  int b = blockIdx.x, t = threadIdx.x;
  int idx = b * SCAN_B + t;
  if (idx < NNODES) row_ptr[idx + 1] += bsum[b];
  if (b == 0 && t == 0) row_ptr[0] = 0;
}

__global__ __launch_bounds__(256) void scatter_k(const int* __restrict__ srcA, const int* __restrict__ dstA,
                                                 const int* __restrict__ row_ptr, int* __restrict__ cnt,
                                                 int* __restrict__ col) {
  int e = blockIdx.x * 256 + threadIdx.x;
  if (e >= ETOT) return;
  int s, d;
  if (e < NEDGES) { s = srcA[e]; d = dstA[e]; }
  else { s = d = e - NEDGES; }
  int pos = row_ptr[d] + atomicAdd(&cnt[d], 1);
  col[pos] = s;
}

// ---------------- layer-1 aggregate: bf16 gather, single pass ----------------
__global__ __launch_bounds__(256) void agg1_k(
    const ushort* __restrict__ xw1b, const float* __restrict__ a1s, const float* __restrict__ a1d,
    const int* __restrict__ row_ptr, const int* __restrict__ col,
    const float* __restrict__ b1, float* __restrict__ hout, int n) {
  int wid = (blockIdx.x * 256 + threadIdx.x) >> 6;
  if (wid >= n) return;
  int lane = threadIdx.x & 63;
  int hh = lane >> 3;
  int beg = row_ptr[wid], end = row_ptr[wid + 1];
  float ad = a1d[(size_t)wid * 8 + hh];
  float denom = 0.f, ax = 0.f, ay = 0.f, az = 0.f, aw = 0.f;
  int i = beg;
  for (; i + 4 <= end; i += 4) {
    int s0 = col[i], s1 = col[i + 1], s2 = col[i + 2], s3 = col[i + 3];
    float e0 = a1s[(size_t)s0 * 8 + hh] + ad;
    float e1 = a1s[(size_t)s1 * 8 + hh] + ad;
    float e2 = a1s[(size_t)s2 * 8 + hh] + ad;
    float e3 = a1s[(size_t)s3 * 8 + hh] + ad;
    ushort4 u0 = *(const ushort4*)(xw1b + (size_t)s0 * 256 + lane * 4);
    ushort4 u1 = *(const ushort4*)(xw1b + (size_t)s1 * 256 + lane * 4);
    ushort4 u2 = *(const ushort4*)(xw1b + (size_t)s2 * 256 + lane * 4);
    ushort4 u3 = *(const ushort4*)(xw1b + (size_t)s3 * 256 + lane * 4);
    float w0 = __expf(fmaxf(e0, 0.f) + NEG * fminf(e0, 0.f));
    float w1 = __expf(fmaxf(e1, 0.f) + NEG * fminf(e1, 0.f));
    float w2 = __expf(fmaxf(e2, 0.f) + NEG * fminf(e2, 0.f));
    float w3 = __expf(fmaxf(e3, 0.f) + NEG * fminf(e3, 0.f));
    denom += (w0 + w1) + (w2 + w3);
    ax += w0 * bf2f(u0.x) + w1 * bf2f(u1.x) + w2 * bf2f(u2.x) + w3 * bf2f(u3.x);
    ay += w0 * bf2f(u0.y) + w1 * bf2f(u1.y) + w2 * bf2f(u2.y) + w3 * bf2f(u3.y);
    az += w0 * bf2f(u0.z) + w1 * bf2f(u1.z) + w2 * bf2f(u2.z) + w3 * bf2f(u3.z);
    aw += w0 * bf2f(u0.w) + w1 * bf2f(u1.w) + w2 * bf2f(u2.w) + w3 * bf2f(u3.w);
  }
  for (; i < end; ++i) {
    int s = col[i];
    float e = a1s[(size_t)s * 8 + hh] + ad;
    float w = __expf(fmaxf(e, 0.f) + NEG * fminf(e, 0.f));
    ushort4 u = *(const ushort4*)(xw1b + (size_t)s * 256 + lane * 4);
    denom += w;
    ax += w * bf2f(u.x); ay += w * bf2f(u.y); az += w * bf2f(u.z); aw += w * bf2f(u.w);
  }
  float inv = 1.f / denom;
  float4 bv = *reinterpret_cast<const float4*>(b1 + lane * 4);
  float ox = ax * inv + bv.x;
  float oy = ay * inv + bv.y;
  float oz = az * inv + bv.z;
  float ow = aw * inv + bv.w;
  ox = (ox > 0.f) ? ox : expm1f(ox);
  oy = (oy > 0.f) ? oy : expm1f(oy);
  oz = (oz > 0.f) ? oz : expm1f(oz);
  ow = (ow > 0.f) ? ow : expm1f(ow);
  *reinterpret_cast<float4*>(hout + (size_t)wid * 256 + lane * 4) =
      make_float4(ox, oy, oz, ow);
}

// ---------------- alpha2 ----------------
__global__ __launch_bounds__(256) void alpha2_k(
    const float* __restrict__ xw2, const float* __restrict__ a2s_in, const float* __restrict__ a2d_in,
    float* __restrict__ os, float* __restrict__ od, int n) {
  int v = blockIdx.x * 256 + threadIdx.x;
  if (v >= n) return;
  float s = 0.f, d = 0.f;
#pragma unroll
  for (int j = 0; j < 10; ++j) {
    float4 xv = *reinterpret_cast<const float4*>(xw2 + (size_t)v * 40 + j * 4);
    float4 as = *reinterpret_cast<const float4*>(a2s_in + j * 4);
    float4 ad = *reinterpret_cast<const float4*>(a2d_in + j * 4);
    s += xv.x * as.x + xv.y * as.y + xv.z * as.z + xv.w * as.w;
    d += xv.x * ad.x + xv.y * ad.y + xv.z * ad.z + xv.w * ad.w;
  }
  os[v] = s;
  od[v] = d;
}

// ---------------- layer-2 aggregate ----------------
__global__ __launch_bounds__(256) void agg2_k(
    const float* __restrict__ xw2, const float* __restrict__ a2s, const float* __restrict__ a2d,
    const int* __restrict__ row_ptr, const int* __restrict__ col,
    const float* __restrict__ b2, float* __restrict__ out, int n) {
  int wid = (blockIdx.x * 256 + threadIdx.x) >> 6;
  if (wid >= n) return;
  int lane = threadIdx.x & 63;
  int beg = row_ptr[wid], end = row_ptr[wid + 1];
  float ad = a2d[wid];
  float denom = 0.f, acc = 0.f;
  int i = beg;
  for (; i + 4 <= end; i += 4) {
    int s0 = col[i], s1 = col[i + 1], s2 = col[i + 2], s3 = col[i + 3];
    float e0 = a2s[s0] + ad;
    float e1 = a2s[s1] + ad;
    float e2 = a2s[s2] + ad;
    float e3 = a2s[s3] + ad;
    float w0 = __expf(fmaxf(e0, 0.f) + NEG * fminf(e0, 0.f));
    float w1 = __expf(fmaxf(e1, 0.f) + NEG * fminf(e1, 0.f));
    float w2 = __expf(fmaxf(e2, 0.f) + NEG * fminf(e2, 0.f));
    float w3 = __expf(fmaxf(e3, 0.f) + NEG * fminf(e3, 0.f));
    float x0 = 0.f, x1 = 0.f, x2 = 0.f, x3 = 0.f;
    if (lane < 40) {
      x0 = xw2[(size_t)s0 * 40 + lane];
      x1 = xw2[(size_t)s1 * 40 + lane];
      x2 = xw2[(size_t)s2 * 40 + lane];
      x3 = xw2[(size_t)s3 * 40 + lane];
    }
    denom += (w0 + w1) + (w2 + w3);
    acc += w0 * x0 + w1 * x1 + w2 * x2 + w3 * x3;
  }
  for (; i < end; ++i) {
    int s = col[i];
    float e = a2s[s] + ad;
    float w = __expf(fmaxf(e, 0.f) + NEG * fminf(e, 0.f));
    denom += w;
    if (lane < 40) acc += w * xw2[(size_t)s * 40 + lane];
  }
  if (lane < 40) out[(size_t)wid * 40 + lane] = acc / denom + b2[lane];
}

extern "C" void kernel_launch(void* const* d_in, const int* in_sizes, int n_in,
                              void* d_out, int out_size, void* d_ws, size_t ws_size,
                              hipStream_t stream) {
  const float* x     = (const float*)d_in[0];
  const int*   ei    = (const int*)d_in[1];
  const float* W1    = (const float*)d_in[2];
  const float* a1src = (const float*)d_in[3];
  const float* a1dst = (const float*)d_in[4];
  const float* b1    = (const float*)d_in[5];
  const float* W2    = (const float*)d_in[6];
  const float* a2src = (const float*)d_in[7];
  const float* a2dst = (const float*)d_in[8];
  const float* b2    = (const float*)d_in[9];
  float* out = (float*)d_out;

  const int* srcA = ei;
  const int* dstA = ei + NEDGES;

  // workspace layout
  ushort* xb   = (ushort*)d_ws;                       // NPAD*256 bf16
  ushort* w1t  = xb + (size_t)NPAD * 256;             // 256*256 bf16
  ushort* xw1b = w1t + 65536;                         // NPAD*256 bf16
  float*  h    = (float*)(xw1b + (size_t)NPAD * 256); // NNODES*256 f32
  float*  a1s  = h + (size_t)NNODES * 256;            // NNODES*8
  float*  a1d  = a1s + (size_t)NNODES * 8;            // NNODES*8
  int* ip      = (int*)(a1d + (size_t)NNODES * 8);
  int* row_ptr = ip;                                  // NNODES+1
  int* cnt     = ip + (NNODES + 1);                   // NNODES
  int* col     = cnt + NNODES;                        // ETOT
  int* bsum    = col + ETOT;                          // NSCB
  // layer-2 scratch aliases xb (dead after gemm1)
  float* xw2 = (float*)xb;                            // NNODES*40
  float* a2s = xw2 + (size_t)NNODES * 40;
  float* a2d = a2s + NNODES;

  hipMemsetAsync(cnt, 0, (size_t)NNODES * sizeof(int), stream);

  conv_x<<<(NPAD * 32) / 256, 256, 0, stream>>>(x, xb);
  conv_w1t<<<256, 256, 0, stream>>>(W1, w1t);
  gemm1_mfma<<<NPAD / 64, 256, 0, stream>>>(xb, w1t, xw1b);

  alpha1_k<<<(NNODES + 3) / 4, 256, 0, stream>>>(xw1b, a1src, a1dst, a1s, a1d, NNODES);

  hist_k<<<(ETOT + 255) / 256, 256, 0, stream>>>(dstA, cnt);
  scan1_k<<<NSCB, SCAN_B, 0, stream>>>(cnt, row_ptr, bsum);
  scan2_k<<<1, 256, 0, stream>>>(bsum);
  scan3_k<<<NSCB, SCAN_B, 0, stream>>>(bsum, row_ptr);
  hipMemsetAsync(cnt, 0, (size_t)NNODES * sizeof(int), stream);
  scatter_k<<<(ETOT + 255) / 256, 256, 0, stream>>>(srcA, dstA, row_ptr, cnt, col);

  agg1_k<<<(NNODES + 3) / 4, 256, 0, stream>>>(xw1b, a1s, a1d, row_ptr, col, b1, h, NNODES);

  {
    dim3 grid((NNODES + BM - 1) / BM, 1);
    gemm_tiled<<<grid, 256, 0, stream>>>(h, W2, xw2, NNODES, NCLS, HEADS * HIDS);
  }

  alpha2_k<<<(NNODES + 255) / 256, 256, 0, stream>>>(xw2, a2src, a2dst, a2s, a2d, NNODES);

  agg2_k<<<(NNODES + 3) / 4, 256, 0, stream>>>(xw2, a2s, a2d, row_ptr, col, b2, out, NNODES);
}

// Round 5
// 267.418 us; speedup vs baseline: 2.3576x; 1.1324x over previous
//
#include <hip/hip_runtime.h>
#include <hip/hip_bf16.h>

#define NNODES 50000
#define NPAD   50048
#define NEDGES 800000
#define ETOT   (NEDGES + NNODES)
#define FIN    256
#define HIDS   32
#define HEADS  8
#define NCLS   40
#define NEG    0.2f

#define SCAN_B 256
#define NSCB   ((NNODES + SCAN_B - 1) / SCAN_B)   // 196

// prep_k block-range constants
#define PB_X    (NPAD * 32 / 256)                 // 6256
#define PB_W1   256
#define PB_W2   64
#define PB_CNT  ((NNODES + 255) / 256)            // 196
#define PB_HPAD ((NPAD - NNODES))                 // 48 blocks (256 cols each)

typedef __attribute__((ext_vector_type(8))) short bf16x8;
typedef __attribute__((ext_vector_type(4))) float f32x4;

__device__ __forceinline__ ushort f2bf(float f) {
  unsigned u = __float_as_uint(f);
  unsigned r = (u + 0x7fffu + ((u >> 16) & 1u)) >> 16;   // RNE
  return (ushort)r;
}
__device__ __forceinline__ float bf2f(ushort u) {
  return __uint_as_float(((unsigned)u) << 16);
}

// ---------------- fused prep: x->bf16, W1->W1t bf16, W2->W2t bf16(64 rows), cnt=0, h-pad=0 ----
__global__ __launch_bounds__(256) void prep_k(
    const float* __restrict__ x, const float* __restrict__ W1, const float* __restrict__ W2,
    ushort* __restrict__ xb, ushort* __restrict__ w1t, ushort* __restrict__ w2t,
    int* __restrict__ cnt, ushort* __restrict__ hb) {
  int b = blockIdx.x, t = threadIdx.x;
  if (b < PB_X) {
    size_t gid = (size_t)b * 256 + t;
    int row = (int)(gid >> 5);
    int c0 = ((int)gid & 31) * 8;
    bf16x8 o;
    if (row < NNODES) {
      const float4* xp = (const float4*)(x + (size_t)row * 256 + c0);
      float4 a = xp[0], bb = xp[1];
      o[0] = (short)f2bf(a.x); o[1] = (short)f2bf(a.y);
      o[2] = (short)f2bf(a.z); o[3] = (short)f2bf(a.w);
      o[4] = (short)f2bf(bb.x); o[5] = (short)f2bf(bb.y);
      o[6] = (short)f2bf(bb.z); o[7] = (short)f2bf(bb.w);
    } else {
      o = (bf16x8)0;
    }
    *(bf16x8*)(xb + (size_t)row * 256 + c0) = o;
  } else if (b < PB_X + PB_W1) {
    int idx = (b - PB_X) * 256 + t;
    int k = idx >> 8, n = idx & 255;
    w1t[(size_t)n * 256 + k] = f2bf(W1[(size_t)k * 256 + n]);
  } else if (b < PB_X + PB_W1 + PB_W2) {
    int idx = (b - PB_X - PB_W1) * 256 + t;
    int n = idx >> 8, k = idx & 255;
    w2t[(size_t)n * 256 + k] = (n < NCLS) ? f2bf(W2[(size_t)k * NCLS + n]) : (ushort)0;
  } else if (b < PB_X + PB_W1 + PB_W2 + PB_CNT) {
    int i = (b - PB_X - PB_W1 - PB_W2) * 256 + t;
    if (i < NNODES) cnt[i] = 0;
  } else {
    int idx = (b - PB_X - PB_W1 - PB_W2 - PB_CNT);
    int row = NNODES + idx;
    hb[(size_t)row * 256 + t] = 0;
  }
}

// ---------------- GEMM1: xw1b[NPAD,256](bf16) = xb @ W1t^T via MFMA ----------------
__global__ __launch_bounds__(256) void gemm1_mfma(
    const ushort* __restrict__ xb, const ushort* __restrict__ w1t, ushort* __restrict__ xw1b) {
  __shared__ ushort As[64 * 40];
  __shared__ ushort Bs[256 * 40];
  const int tid = threadIdx.x;
  const int m0 = blockIdx.x * 64;
  const int w = tid >> 6, l = tid & 63, lr = l & 15, lq = l >> 4;
  f32x4 acc[4][4];
#pragma unroll
  for (int i = 0; i < 4; ++i)
#pragma unroll
    for (int j = 0; j < 4; ++j) acc[i][j] = (f32x4)0.f;

  for (int k0 = 0; k0 < 256; k0 += 32) {
    {
      int row = tid >> 2, kg = (tid & 3) * 8;
      *(bf16x8*)&As[row * 40 + kg] = *(const bf16x8*)(xb + (size_t)(m0 + row) * 256 + k0 + kg);
    }
#pragma unroll
    for (int p = 0; p < 4; ++p) {
      int idx = tid + p * 256;
      int n = idx >> 2, kg = (idx & 3) * 8;
      *(bf16x8*)&Bs[n * 40 + kg] = *(const bf16x8*)(w1t + (size_t)n * 256 + k0 + kg);
    }
    __syncthreads();
    bf16x8 af[4], bf[4];
#pragma unroll
    for (int mt = 0; mt < 4; ++mt)
      af[mt] = *(const bf16x8*)&As[(mt * 16 + lr) * 40 + lq * 8];
#pragma unroll
    for (int nt = 0; nt < 4; ++nt)
      bf[nt] = *(const bf16x8*)&Bs[((w * 4 + nt) * 16 + lr) * 40 + lq * 8];
#pragma unroll
    for (int mt = 0; mt < 4; ++mt)
#pragma unroll
      for (int nt = 0; nt < 4; ++nt)
        acc[mt][nt] = __builtin_amdgcn_mfma_f32_16x16x32_bf16(af[mt], bf[nt], acc[mt][nt], 0, 0, 0);
    __syncthreads();
  }
#pragma unroll
  for (int mt = 0; mt < 4; ++mt)
#pragma unroll
    for (int nt = 0; nt < 4; ++nt)
#pragma unroll
      for (int r = 0; r < 4; ++r) {
        int row = m0 + mt * 16 + lq * 4 + r;
        int col = (w * 4 + nt) * 16 + lr;
        xw1b[(size_t)row * 256 + col] = f2bf(acc[mt][nt][r]);
      }
}

// ---------------- GEMM2: xw2b[NPAD,40](bf16) = hb @ W2t^T via MFMA, LDS-free ----------------
__global__ __launch_bounds__(256) void gemm2_mfma(
    const ushort* __restrict__ hb, const ushort* __restrict__ w2t, ushort* __restrict__ xw2b) {
  const int tid = threadIdx.x;
  const int w = tid >> 6, l = tid & 63, lr = l & 15, lq = l >> 4;
  const int row0 = blockIdx.x * 64 + w * 16;
  f32x4 acc[4];
#pragma unroll
  for (int i = 0; i < 4; ++i) acc[i] = (f32x4)0.f;
#pragma unroll
  for (int ks = 0; ks < 8; ++ks) {
    int k0 = ks * 32;
    bf16x8 af = *(const bf16x8*)(hb + (size_t)(row0 + lr) * 256 + k0 + lq * 8);
#pragma unroll
    for (int nt = 0; nt < 4; ++nt) {
      bf16x8 bfr = *(const bf16x8*)(w2t + (size_t)(nt * 16 + lr) * 256 + k0 + lq * 8);
      acc[nt] = __builtin_amdgcn_mfma_f32_16x16x32_bf16(af, bfr, acc[nt], 0, 0, 0);
    }
  }
#pragma unroll
  for (int nt = 0; nt < 4; ++nt) {
    int col = nt * 16 + lr;
    if (col < NCLS) {
#pragma unroll
      for (int r = 0; r < 4; ++r) {
        int row = row0 + lq * 4 + r;
        xw2b[(size_t)row * 40 + col] = f2bf(acc[nt][r]);
      }
    }
  }
}

// ---------------- alpha1 (reads bf16 xw1) ----------------
__global__ __launch_bounds__(256) void alpha1_k(
    const ushort* __restrict__ xw1b, const float* __restrict__ a1src,
    const float* __restrict__ a1dst, float* __restrict__ os, float* __restrict__ od, int n) {
  int wid = (blockIdx.x * 256 + threadIdx.x) >> 6;
  if (wid >= n) return;
  int lane = threadIdx.x & 63;
  ushort4 u = *(const ushort4*)(xw1b + (size_t)wid * 256 + lane * 4);
  float4 xv = make_float4(bf2f(u.x), bf2f(u.y), bf2f(u.z), bf2f(u.w));
  float4 as = *reinterpret_cast<const float4*>(a1src + lane * 4);
  float4 ad = *reinterpret_cast<const float4*>(a1dst + lane * 4);
  float s = xv.x * as.x + xv.y * as.y + xv.z * as.z + xv.w * as.w;
  float d = xv.x * ad.x + xv.y * ad.y + xv.z * ad.z + xv.w * ad.w;
#pragma unroll
  for (int off = 1; off < 8; off <<= 1) {
    s += __shfl_xor(s, off, 64);
    d += __shfl_xor(d, off, 64);
  }
  if ((lane & 7) == 0) {
    os[(size_t)wid * 8 + (lane >> 3)] = s;
    od[(size_t)wid * 8 + (lane >> 3)] = d;
  }
}

// ---------------- CSR build ----------------
__global__ __launch_bounds__(256) void hist_k(const int* __restrict__ dstA, int* __restrict__ cnt) {
  int e = blockIdx.x * 256 + threadIdx.x;
  if (e >= ETOT) return;
  int d = (e < NEDGES) ? dstA[e] : (e - NEDGES);
  atomicAdd(&cnt[d], 1);
}

__global__ __launch_bounds__(SCAN_B) void scan1_k(const int* __restrict__ deg,
                                                  int* __restrict__ row_ptr,
                                                  int* __restrict__ bsum) {
  __shared__ int sm[SCAN_B];
  int b = blockIdx.x, t = threadIdx.x;
  int idx = b * SCAN_B + t;
  int v = (idx < NNODES) ? deg[idx] : 0;
  sm[t] = v;
  __syncthreads();
#pragma unroll
  for (int off = 1; off < SCAN_B; off <<= 1) {
    int u = (t >= off) ? sm[t - off] : 0;
    __syncthreads();
    sm[t] += u;
    __syncthreads();
  }
  if (idx < NNODES) row_ptr[idx + 1] = sm[t];
  if (t == SCAN_B - 1) bsum[b] = sm[t];
}

__global__ __launch_bounds__(256) void scan2_k(int* __restrict__ bsum) {
  __shared__ int sm[256];
  int t = threadIdx.x;
  sm[t] = (t < NSCB) ? bsum[t] : 0;
  __syncthreads();
#pragma unroll
  for (int off = 1; off < 256; off <<= 1) {
    int u = (t >= off) ? sm[t - off] : 0;
    __syncthreads();
    sm[t] += u;
    __syncthreads();
  }
  if (t < NSCB) bsum[t] = (t > 0) ? sm[t - 1] : 0;
}

__global__ __launch_bounds__(SCAN_B) void scan3_k(const int* __restrict__ bsum,
                                                  int* __restrict__ row_ptr) {
  int b = blockIdx.x, t = threadIdx.x;
  int idx = b * SCAN_B + t;
  if (idx < NNODES) row_ptr[idx + 1] += bsum[b];
  if (b == 0 && t == 0) row_ptr[0] = 0;
}

// scatter via atomicSub: cnt holds degrees on entry, zeros on exit (self-restoring)
__global__ __launch_bounds__(256) void scatter_k(const int* __restrict__ srcA, const int* __restrict__ dstA,
                                                 const int* __restrict__ row_ptr, int* __restrict__ cnt,
                                                 int* __restrict__ col) {
  int e = blockIdx.x * 256 + threadIdx.x;
  if (e >= ETOT) return;
  int s, d;
  if (e < NEDGES) { s = srcA[e]; d = dstA[e]; }
  else { s = d = e - NEDGES; }
  int old = atomicSub(&cnt[d], 1);
  col[row_ptr[d] + old - 1] = s;
}

// ---------------- layer-1 aggregate: bf16 gather, bf16 h output ----------------
__global__ __launch_bounds__(256) void agg1_k(
    const ushort* __restrict__ xw1b, const float* __restrict__ a1s, const float* __restrict__ a1d,
    const int* __restrict__ row_ptr, const int* __restrict__ col,
    const float* __restrict__ b1, ushort* __restrict__ hb, int n) {
  int wid = (blockIdx.x * 256 + threadIdx.x) >> 6;
  if (wid >= n) return;
  int lane = threadIdx.x & 63;
  int hh = lane >> 3;
  int beg = row_ptr[wid], end = row_ptr[wid + 1];
  float ad = a1d[(size_t)wid * 8 + hh];
  float denom = 0.f, ax = 0.f, ay = 0.f, az = 0.f, aw = 0.f;
  int i = beg;
  for (; i + 4 <= end; i += 4) {
    int s0 = col[i], s1 = col[i + 1], s2 = col[i + 2], s3 = col[i + 3];
    float e0 = a1s[(size_t)s0 * 8 + hh] + ad;
    float e1 = a1s[(size_t)s1 * 8 + hh] + ad;
    float e2 = a1s[(size_t)s2 * 8 + hh] + ad;
    float e3 = a1s[(size_t)s3 * 8 + hh] + ad;
    ushort4 u0 = *(const ushort4*)(xw1b + (size_t)s0 * 256 + lane * 4);
    ushort4 u1 = *(const ushort4*)(xw1b + (size_t)s1 * 256 + lane * 4);
    ushort4 u2 = *(const ushort4*)(xw1b + (size_t)s2 * 256 + lane * 4);
    ushort4 u3 = *(const ushort4*)(xw1b + (size_t)s3 * 256 + lane * 4);
    float w0 = __expf(fmaxf(e0, 0.f) + NEG * fminf(e0, 0.f));
    float w1 = __expf(fmaxf(e1, 0.f) + NEG * fminf(e1, 0.f));
    float w2 = __expf(fmaxf(e2, 0.f) + NEG * fminf(e2, 0.f));
    float w3 = __expf(fmaxf(e3, 0.f) + NEG * fminf(e3, 0.f));
    denom += (w0 + w1) + (w2 + w3);
    ax += w0 * bf2f(u0.x) + w1 * bf2f(u1.x) + w2 * bf2f(u2.x) + w3 * bf2f(u3.x);
    ay += w0 * bf2f(u0.y) + w1 * bf2f(u1.y) + w2 * bf2f(u2.y) + w3 * bf2f(u3.y);
    az += w0 * bf2f(u0.z) + w1 * bf2f(u1.z) + w2 * bf2f(u2.z) + w3 * bf2f(u3.z);
    aw += w0 * bf2f(u0.w) + w1 * bf2f(u1.w) + w2 * bf2f(u2.w) + w3 * bf2f(u3.w);
  }
  for (; i < end; ++i) {
    int s = col[i];
    float e = a1s[(size_t)s * 8 + hh] + ad;
    float w = __expf(fmaxf(e, 0.f) + NEG * fminf(e, 0.f));
    ushort4 u = *(const ushort4*)(xw1b + (size_t)s * 256 + lane * 4);
    denom += w;
    ax += w * bf2f(u.x); ay += w * bf2f(u.y); az += w * bf2f(u.z); aw += w * bf2f(u.w);
  }
  float inv = 1.f / denom;
  float4 bv = *reinterpret_cast<const float4*>(b1 + lane * 4);
  float ox = ax * inv + bv.x;
  float oy = ay * inv + bv.y;
  float oz = az * inv + bv.z;
  float ow = aw * inv + bv.w;
  ox = (ox > 0.f) ? ox : expm1f(ox);
  oy = (oy > 0.f) ? oy : expm1f(oy);
  oz = (oz > 0.f) ? oz : expm1f(oz);
  ow = (ow > 0.f) ? ow : expm1f(ow);
  ushort4 ho;
  ho.x = f2bf(ox); ho.y = f2bf(oy); ho.z = f2bf(oz); ho.w = f2bf(ow);
  *(ushort4*)(hb + (size_t)wid * 256 + lane * 4) = ho;
}

// ---------------- alpha2 (reads bf16 xw2, pitch 40) ----------------
__global__ __launch_bounds__(256) void alpha2_k(
    const ushort* __restrict__ xw2b, const float* __restrict__ a2s_in, const float* __restrict__ a2d_in,
    float* __restrict__ os, float* __restrict__ od, int n) {
  int v = blockIdx.x * 256 + threadIdx.x;
  if (v >= n) return;
  const ushort* row = xw2b + (size_t)v * 40;
  float s = 0.f, d = 0.f;
#pragma unroll
  for (int j = 0; j < 10; ++j) {
    ushort4 u = *(const ushort4*)(row + j * 4);
    float4 as = *reinterpret_cast<const float4*>(a2s_in + j * 4);
    float4 ad = *reinterpret_cast<const float4*>(a2d_in + j * 4);
    s += bf2f(u.x) * as.x + bf2f(u.y) * as.y + bf2f(u.z) * as.z + bf2f(u.w) * as.w;
    d += bf2f(u.x) * ad.x + bf2f(u.y) * ad.y + bf2f(u.z) * ad.z + bf2f(u.w) * ad.w;
  }
  os[v] = s;
  od[v] = d;
}

// ---------------- layer-2 aggregate (bf16 gather, pitch 40) ----------------
__global__ __launch_bounds__(256) void agg2_k(
    const ushort* __restrict__ xw2b, const float* __restrict__ a2s, const float* __restrict__ a2d,
    const int* __restrict__ row_ptr, const int* __restrict__ col,
    const float* __restrict__ b2, float* __restrict__ out, int n) {
  int wid = (blockIdx.x * 256 + threadIdx.x) >> 6;
  if (wid >= n) return;
  int lane = threadIdx.x & 63;
  int beg = row_ptr[wid], end = row_ptr[wid + 1];
  float ad = a2d[wid];
  float denom = 0.f, acc = 0.f;
  int i = beg;
  for (; i + 4 <= end; i += 4) {
    int s0 = col[i], s1 = col[i + 1], s2 = col[i + 2], s3 = col[i + 3];
    float e0 = a2s[s0] + ad;
    float e1 = a2s[s1] + ad;
    float e2 = a2s[s2] + ad;
    float e3 = a2s[s3] + ad;
    float w0 = __expf(fmaxf(e0, 0.f) + NEG * fminf(e0, 0.f));
    float w1 = __expf(fmaxf(e1, 0.f) + NEG * fminf(e1, 0.f));
    float w2 = __expf(fmaxf(e2, 0.f) + NEG * fminf(e2, 0.f));
    float w3 = __expf(fmaxf(e3, 0.f) + NEG * fminf(e3, 0.f));
    float x0 = 0.f, x1 = 0.f, x2 = 0.f, x3 = 0.f;
    if (lane < NCLS) {
      x0 = bf2f(xw2b[(size_t)s0 * 40 + lane]);
      x1 = bf2f(xw2b[(size_t)s1 * 40 + lane]);
      x2 = bf2f(xw2b[(size_t)s2 * 40 + lane]);
      x3 = bf2f(xw2b[(size_t)s3 * 40 + lane]);
    }
    denom += (w0 + w1) + (w2 + w3);
    acc += w0 * x0 + w1 * x1 + w2 * x2 + w3 * x3;
  }
  for (; i < end; ++i) {
    int s = col[i];
    float e = a2s[s] + ad;
    float w = __expf(fmaxf(e, 0.f) + NEG * fminf(e, 0.f));
    denom += w;
    if (lane < NCLS) acc += w * bf2f(xw2b[(size_t)s * 40 + lane]);
  }
  if (lane < NCLS) out[(size_t)wid * 40 + lane] = acc / denom + b2[lane];
}

extern "C" void kernel_launch(void* const* d_in, const int* in_sizes, int n_in,
                              void* d_out, int out_size, void* d_ws, size_t ws_size,
                              hipStream_t stream) {
  const float* x     = (const float*)d_in[0];
  const int*   ei    = (const int*)d_in[1];
  const float* W1    = (const float*)d_in[2];
  const float* a1src = (const float*)d_in[3];
  const float* a1dst = (const float*)d_in[4];
  const float* b1    = (const float*)d_in[5];
  const float* W2    = (const float*)d_in[6];
  const float* a2src = (const float*)d_in[7];
  const float* a2dst = (const float*)d_in[8];
  const float* b2    = (const float*)d_in[9];
  float* out = (float*)d_out;

  const int* srcA = ei;
  const int* dstA = ei + NEDGES;

  // workspace layout (all 16B-aligned segment starts)
  ushort* xb   = (ushort*)d_ws;                     // NPAD*256
  ushort* w1t  = xb + (size_t)NPAD * 256;           // 256*256
  ushort* w2t  = w1t + 65536;                       // 64*256
  ushort* xw1b = w2t + 16384;                       // NPAD*256
  ushort* hb   = xw1b + (size_t)NPAD * 256;         // NPAD*256
  ushort* xw2b = hb + (size_t)NPAD * 256;           // NPAD*40
  float* a1s   = (float*)(xw2b + (size_t)NPAD * 40);
  float* a1d   = a1s + (size_t)NNODES * 8;
  float* a2s   = a1d + (size_t)NNODES * 8;
  float* a2d   = a2s + NNODES;
  int* row_ptr = (int*)(a2d + NNODES);              // NNODES+1
  int* cnt     = row_ptr + (NNODES + 1);            // NNODES
  int* col     = cnt + NNODES;                      // ETOT
  int* bsum    = col + ETOT;                        // NSCB

  prep_k<<<PB_X + PB_W1 + PB_W2 + PB_CNT + PB_HPAD, 256, 0, stream>>>(
      x, W1, W2, xb, w1t, w2t, cnt, hb);

  gemm1_mfma<<<NPAD / 64, 256, 0, stream>>>(xb, w1t, xw1b);

  alpha1_k<<<(NNODES + 3) / 4, 256, 0, stream>>>(xw1b, a1src, a1dst, a1s, a1d, NNODES);

  hist_k<<<(ETOT + 255) / 256, 256, 0, stream>>>(dstA, cnt);
  scan1_k<<<NSCB, SCAN_B, 0, stream>>>(cnt, row_ptr, bsum);
  scan2_k<<<1, 256, 0, stream>>>(bsum);
  scan3_k<<<NSCB, SCAN_B, 0, stream>>>(bsum, row_ptr);
  scatter_k<<<(ETOT + 255) / 256, 256, 0, stream>>>(srcA, dstA, row_ptr, cnt, col);

  agg1_k<<<(NNODES + 3) / 4, 256, 0, stream>>>(xw1b, a1s, a1d, row_ptr, col, b1, hb, NNODES);

  gemm2_mfma<<<NPAD / 64, 256, 0, stream>>>(hb, w2t, xw2b);

  alpha2_k<<<(NNODES + 255) / 256, 256, 0, stream>>>(xw2b, a2src, a2dst, a2s, a2d, NNODES);

  agg2_k<<<(NNODES + 3) / 4, 256, 0, stream>>>(xw2b, a2s, a2d, row_ptr, col, b2, out, NNODES);
}

// Round 6
// 266.129 us; speedup vs baseline: 2.3691x; 1.0048x over previous
//
#include <hip/hip_runtime.h>
#include <hip/hip_bf16.h>

#define NNODES 50000
#define NPAD   50048
#define NEDGES 800000
#define ETOT   (NEDGES + NNODES)
#define FIN    256
#define HIDS   32
#define HEADS  8
#define NCLS   40
#define NEG    0.2f

#define SCAN_B 256
#define NSCB   ((NNODES + SCAN_B - 1) / SCAN_B)   // 196

typedef __attribute__((ext_vector_type(8))) short bf16x8;
typedef __attribute__((ext_vector_type(4))) float f32x4;

__device__ __forceinline__ ushort f2bf(float f) {
  unsigned u = __float_as_uint(f);
  unsigned r = (u + 0x7fffu + ((u >> 16) & 1u)) >> 16;   // RNE
  return (ushort)r;
}
__device__ __forceinline__ float bf2f(ushort u) {
  return __uint_as_float(((unsigned)u) << 16);
}

// ---------------- prep: w1t[320][256] (W1^T + 16 fused-alpha rows + zero pad),
//                  w2t[64][256] (W2^T cols 0..39, rows 40/41 = W2@a2src/dst, pad 0),
//                  cnt=0, hb pad rows = 0 ----------------
// blocks: [0,256) w1t convert | [256,272) w1a | [272,320) w1 zero rows |
//         [320,384) w2t | [384,580) cnt | [580,628) hb pad
__global__ __launch_bounds__(256) void prep_k(
    const float* __restrict__ W1, const float* __restrict__ W2,
    const float* __restrict__ a1src, const float* __restrict__ a1dst,
    const float* __restrict__ a2src, const float* __restrict__ a2dst,
    ushort* __restrict__ w1t, ushort* __restrict__ w2t,
    int* __restrict__ cnt, ushort* __restrict__ hb) {
  int b = blockIdx.x, t = threadIdx.x;
  if (b < 256) {
    int k = b, n = t;
    w1t[(size_t)n * 256 + k] = f2bf(W1[(size_t)k * 256 + n]);
  } else if (b < 272) {
    int j = b - 256, k = t;
    const float* av = (j < 8) ? (a1src + j * 32) : (a1dst + (j - 8) * 32);
    int nb = (j < 8) ? j * 32 : (j - 8) * 32;
    float s = 0.f;
#pragma unroll
    for (int c = 0; c < 32; ++c) s += W1[(size_t)k * 256 + nb + c] * av[c];
    w1t[(size_t)(256 + j) * 256 + k] = f2bf(s);
  } else if (b < 320) {
    w1t[(size_t)b * 256 + t] = 0;     // rows 272..319 zero
  } else if (b < 384) {
    int n = b - 320, k = t;
    ushort v;
    if (n < NCLS) {
      v = f2bf(W2[(size_t)k * NCLS + n]);
    } else if (n == 40) {
      float s = 0.f;
#pragma unroll
      for (int c = 0; c < NCLS; ++c) s += W2[(size_t)k * NCLS + c] * a2src[c];
      v = f2bf(s);
    } else if (n == 41) {
      float s = 0.f;
#pragma unroll
      for (int c = 0; c < NCLS; ++c) s += W2[(size_t)k * NCLS + c] * a2dst[c];
      v = f2bf(s);
    } else {
      v = 0;
    }
    w2t[(size_t)n * 256 + k] = v;
  } else if (b < 580) {
    int i = (b - 384) * 256 + t;
    if (i < NNODES) cnt[i] = 0;
  } else {
    int r = NNODES + (b - 580);
    hb[(size_t)r * 256 + t] = 0;
  }
}

// ---------------- GEMM1: [xw1b | a1s | a1d] = x(f32->bf16) @ w1t[320]^T via MFMA ------
// BM=64, 20 n-tiles, 4 waves x 5 tiles (tile = nt*4 + w), BK=32
__global__ __launch_bounds__(256) void gemm1_mfma(
    const float* __restrict__ x, const ushort* __restrict__ w1t,
    ushort* __restrict__ xw1b, float* __restrict__ a1s, float* __restrict__ a1d) {
  __shared__ ushort As[64 * 40];
  __shared__ ushort Bs[320 * 40];
  const int tid = threadIdx.x;
  const int m0 = blockIdx.x * 64;
  const int w = tid >> 6, l = tid & 63, lr = l & 15, lq = l >> 4;
  f32x4 acc[4][5];
#pragma unroll
  for (int i = 0; i < 4; ++i)
#pragma unroll
    for (int j = 0; j < 5; ++j) acc[i][j] = (f32x4)0.f;

  for (int k0 = 0; k0 < 256; k0 += 32) {
    {
      int row = tid >> 2, kg = (tid & 3) * 8;
      int gr = m0 + row;
      bf16x8 av;
      if (gr < NNODES) {
        const float4* xp = (const float4*)(x + (size_t)gr * 256 + k0 + kg);
        float4 p0 = xp[0], p1 = xp[1];
        av[0] = (short)f2bf(p0.x); av[1] = (short)f2bf(p0.y);
        av[2] = (short)f2bf(p0.z); av[3] = (short)f2bf(p0.w);
        av[4] = (short)f2bf(p1.x); av[5] = (short)f2bf(p1.y);
        av[6] = (short)f2bf(p1.z); av[7] = (short)f2bf(p1.w);
      } else {
        av = (bf16x8)0;
      }
      *(bf16x8*)&As[row * 40 + kg] = av;
    }
#pragma unroll
    for (int p = 0; p < 5; ++p) {
      int idx = tid + p * 256;
      int n = idx >> 2, kg = (idx & 3) * 8;
      *(bf16x8*)&Bs[n * 40 + kg] = *(const bf16x8*)(w1t + (size_t)n * 256 + k0 + kg);
    }
    __syncthreads();
    bf16x8 af[4], bfr[5];
#pragma unroll
    for (int mt = 0; mt < 4; ++mt)
      af[mt] = *(const bf16x8*)&As[(mt * 16 + lr) * 40 + lq * 8];
#pragma unroll
    for (int nt = 0; nt < 5; ++nt) {
      int tile = nt * 4 + w;
      bfr[nt] = *(const bf16x8*)&Bs[(tile * 16 + lr) * 40 + lq * 8];
    }
#pragma unroll
    for (int mt = 0; mt < 4; ++mt)
#pragma unroll
      for (int nt = 0; nt < 5; ++nt)
        acc[mt][nt] = __builtin_amdgcn_mfma_f32_16x16x32_bf16(af[mt], bfr[nt], acc[mt][nt], 0, 0, 0);
    __syncthreads();
  }
#pragma unroll
  for (int mt = 0; mt < 4; ++mt)
#pragma unroll
    for (int nt = 0; nt < 5; ++nt) {
      int tile = nt * 4 + w;
      if (tile < 16) {
        int colc = tile * 16 + lr;
#pragma unroll
        for (int r = 0; r < 4; ++r) {
          int row = m0 + mt * 16 + lq * 4 + r;
          xw1b[(size_t)row * 256 + colc] = f2bf(acc[mt][nt][r]);
        }
      } else if (tile == 16) {
#pragma unroll
        for (int r = 0; r < 4; ++r) {
          int row = m0 + mt * 16 + lq * 4 + r;
          if (row < NNODES) {
            if (lr < 8) a1s[(size_t)row * 8 + lr] = acc[mt][nt][r];
            else        a1d[(size_t)row * 8 + lr - 8] = acc[mt][nt][r];
          }
        }
      }
      // tiles 17..19: zero columns, discard
    }
}

// ---------------- GEMM2: [xw2b | a2s | a2d] = hb @ w2t^T via MFMA, LDS-free -----------
__global__ __launch_bounds__(256) void gemm2_mfma(
    const ushort* __restrict__ hb, const ushort* __restrict__ w2t,
    ushort* __restrict__ xw2b, float* __restrict__ a2s, float* __restrict__ a2d) {
  const int tid = threadIdx.x;
  const int w = tid >> 6, l = tid & 63, lr = l & 15, lq = l >> 4;
  const int row0 = blockIdx.x * 64 + w * 16;
  f32x4 acc[3];
#pragma unroll
  for (int i = 0; i < 3; ++i) acc[i] = (f32x4)0.f;
#pragma unroll
  for (int ks = 0; ks < 8; ++ks) {
    int k0 = ks * 32;
    bf16x8 af = *(const bf16x8*)(hb + (size_t)(row0 + lr) * 256 + k0 + lq * 8);
#pragma unroll
    for (int nt = 0; nt < 3; ++nt) {
      bf16x8 bfr = *(const bf16x8*)(w2t + (size_t)(nt * 16 + lr) * 256 + k0 + lq * 8);
      acc[nt] = __builtin_amdgcn_mfma_f32_16x16x32_bf16(af, bfr, acc[nt], 0, 0, 0);
    }
  }
#pragma unroll
  for (int nt = 0; nt < 3; ++nt) {
    int colc = nt * 16 + lr;
#pragma unroll
    for (int r = 0; r < 4; ++r) {
      int row = row0 + lq * 4 + r;
      if (colc < NCLS)      xw2b[(size_t)row * 40 + colc] = f2bf(acc[nt][r]);
      else if (colc == 40)  a2s[row] = acc[nt][r];
      else if (colc == 41)  a2d[row] = acc[nt][r];
    }
  }
}

// ---------------- CSR build ----------------
__global__ __launch_bounds__(256) void hist_k(const int* __restrict__ dstA, int* __restrict__ cnt) {
  int e = blockIdx.x * 256 + threadIdx.x;
  if (e >= ETOT) return;
  int d = (e < NEDGES) ? dstA[e] : (e - NEDGES);
  atomicAdd(&cnt[d], 1);
}

__global__ __launch_bounds__(SCAN_B) void scan1_k(const int* __restrict__ deg,
                                                  int* __restrict__ row_ptr,
                                                  int* __restrict__ bsum) {
  __shared__ int sm[SCAN_B];
  int b = blockIdx.x, t = threadIdx.x;
  int idx = b * SCAN_B + t;
  int v = (idx < NNODES) ? deg[idx] : 0;
  sm[t] = v;
  __syncthreads();
#pragma unroll
  for (int off = 1; off < SCAN_B; off <<= 1) {
    int u = (t >= off) ? sm[t - off] : 0;
    __syncthreads();
    sm[t] += u;
    __syncthreads();
  }
  if (idx < NNODES) row_ptr[idx + 1] = sm[t];
  if (t == SCAN_B - 1) bsum[b] = sm[t];
}

__global__ __launch_bounds__(256) void scan2_k(int* __restrict__ bsum) {
  __shared__ int sm[256];
  int t = threadIdx.x;
  sm[t] = (t < NSCB) ? bsum[t] : 0;
  __syncthreads();
#pragma unroll
  for (int off = 1; off < 256; off <<= 1) {
    int u = (t >= off) ? sm[t - off] : 0;
    __syncthreads();
    sm[t] += u;
    __syncthreads();
  }
  if (t < NSCB) bsum[t] = (t > 0) ? sm[t - 1] : 0;
}

__global__ __launch_bounds__(SCAN_B) void scan3_k(const int* __restrict__ bsum,
                                                  int* __restrict__ row_ptr) {
  int b = blockIdx.x, t = threadIdx.x;
  int idx = b * SCAN_B + t;
  if (idx < NNODES) row_ptr[idx + 1] += bsum[b];
  if (b == 0 && t == 0) row_ptr[0] = 0;
}

// scatter via atomicSub: cnt holds degrees on entry, zeros on exit
__global__ __launch_bounds__(256) void scatter_k(const int* __restrict__ srcA, const int* __restrict__ dstA,
                                                 const int* __restrict__ row_ptr, int* __restrict__ cnt,
                                                 int* __restrict__ col) {
  int e = blockIdx.x * 256 + threadIdx.x;
  if (e >= ETOT) return;
  int s, d;
  if (e < NEDGES) { s = srcA[e]; d = dstA[e]; }
  else { s = d = e - NEDGES; }
  int old = atomicSub(&cnt[d], 1);
  col[row_ptr[d] + old - 1] = s;
}

// ---------------- layer-1 aggregate: 2 waves per node, LDS combine ----------------
__global__ __launch_bounds__(256) void agg1_k(
    const ushort* __restrict__ xw1b, const float* __restrict__ a1s, const float* __restrict__ a1d,
    const int* __restrict__ row_ptr, const int* __restrict__ col,
    const float* __restrict__ b1, ushort* __restrict__ hb) {
  __shared__ float4 ps[2][64];
  __shared__ float pd[2][64];
  const int tid = threadIdx.x;
  const int wave = tid >> 6, lane = tid & 63;
  const int nl = wave >> 1, sub = wave & 1;
  const int node = blockIdx.x * 2 + nl;
  const int hh = lane >> 3;
  int beg = row_ptr[node], end = row_ptr[node + 1];
  int half = (end - beg + 1) >> 1;
  int i = beg + sub * half;
  int lim = sub ? end : (beg + half);
  float ad = a1d[(size_t)node * 8 + hh];
  float denom = 0.f, ax = 0.f, ay = 0.f, az = 0.f, aw = 0.f;
  for (; i + 4 <= lim; i += 4) {
    int s0 = col[i], s1 = col[i + 1], s2 = col[i + 2], s3 = col[i + 3];
    float e0 = a1s[(size_t)s0 * 8 + hh] + ad;
    float e1 = a1s[(size_t)s1 * 8 + hh] + ad;
    float e2 = a1s[(size_t)s2 * 8 + hh] + ad;
    float e3 = a1s[(size_t)s3 * 8 + hh] + ad;
    ushort4 u0 = *(const ushort4*)(xw1b + (size_t)s0 * 256 + lane * 4);
    ushort4 u1 = *(const ushort4*)(xw1b + (size_t)s1 * 256 + lane * 4);
    ushort4 u2 = *(const ushort4*)(xw1b + (size_t)s2 * 256 + lane * 4);
    ushort4 u3 = *(const ushort4*)(xw1b + (size_t)s3 * 256 + lane * 4);
    float w0 = __expf(fmaxf(e0, 0.f) + NEG * fminf(e0, 0.f));
    float w1 = __expf(fmaxf(e1, 0.f) + NEG * fminf(e1, 0.f));
    float w2 = __expf(fmaxf(e2, 0.f) + NEG * fminf(e2, 0.f));
    float w3 = __expf(fmaxf(e3, 0.f) + NEG * fminf(e3, 0.f));
    denom += (w0 + w1) + (w2 + w3);
    ax += w0 * bf2f(u0.x) + w1 * bf2f(u1.x) + w2 * bf2f(u2.x) + w3 * bf2f(u3.x);
    ay += w0 * bf2f(u0.y) + w1 * bf2f(u1.y) + w2 * bf2f(u2.y) + w3 * bf2f(u3.y);
    az += w0 * bf2f(u0.z) + w1 * bf2f(u1.z) + w2 * bf2f(u2.z) + w3 * bf2f(u3.z);
    aw += w0 * bf2f(u0.w) + w1 * bf2f(u1.w) + w2 * bf2f(u2.w) + w3 * bf2f(u3.w);
  }
  for (; i < lim; ++i) {
    int s = col[i];
    float e = a1s[(size_t)s * 8 + hh] + ad;
    float w = __expf(fmaxf(e, 0.f) + NEG * fminf(e, 0.f));
    ushort4 u = *(const ushort4*)(xw1b + (size_t)s * 256 + lane * 4);
    denom += w;
    ax += w * bf2f(u.x); ay += w * bf2f(u.y); az += w * bf2f(u.z); aw += w * bf2f(u.w);
  }
  if (sub) {
    ps[nl][lane] = make_float4(ax, ay, az, aw);
    pd[nl][lane] = denom;
  }
  __syncthreads();
  if (!sub) {
    float4 o = ps[nl][lane];
    ax += o.x; ay += o.y; az += o.z; aw += o.w;
    denom += pd[nl][lane];
    float inv = 1.f / denom;
    float4 bv = *reinterpret_cast<const float4*>(b1 + lane * 4);
    float ox = ax * inv + bv.x;
    float oy = ay * inv + bv.y;
    float oz = az * inv + bv.z;
    float ow = aw * inv + bv.w;
    ox = (ox > 0.f) ? ox : expm1f(ox);
    oy = (oy > 0.f) ? oy : expm1f(oy);
    oz = (oz > 0.f) ? oz : expm1f(oz);
    ow = (ow > 0.f) ? ow : expm1f(ow);
    ushort4 ho;
    ho.x = f2bf(ox); ho.y = f2bf(oy); ho.z = f2bf(oz); ho.w = f2bf(ow);
    *(ushort4*)(hb + (size_t)node * 256 + lane * 4) = ho;
  }
}

// ---------------- layer-2 aggregate: 2 waves per node, LDS combine ----------------
__global__ __launch_bounds__(256) void agg2_k(
    const ushort* __restrict__ xw2b, const float* __restrict__ a2s, const float* __restrict__ a2d,
    const int* __restrict__ row_ptr, const int* __restrict__ col,
    const float* __restrict__ b2, float* __restrict__ out) {
  __shared__ float ps[2][40];
  __shared__ float pd[2];
  const int tid = threadIdx.x;
  const int wave = tid >> 6, lane = tid & 63;
  const int nl = wave >> 1, sub = wave & 1;
  const int node = blockIdx.x * 2 + nl;
  int beg = row_ptr[node], end = row_ptr[node + 1];
  int half = (end - beg + 1) >> 1;
  int i = beg + sub * half;
  int lim = sub ? end : (beg + half);
  float ad = a2d[node];
  float denom = 0.f, acc = 0.f;
  for (; i + 4 <= lim; i += 4) {
    int s0 = col[i], s1 = col[i + 1], s2 = col[i + 2], s3 = col[i + 3];
    float e0 = a2s[s0] + ad;
    float e1 = a2s[s1] + ad;
    float e2 = a2s[s2] + ad;
    float e3 = a2s[s3] + ad;
    float w0 = __expf(fmaxf(e0, 0.f) + NEG * fminf(e0, 0.f));
    float w1 = __expf(fmaxf(e1, 0.f) + NEG * fminf(e1, 0.f));
    float w2 = __expf(fmaxf(e2, 0.f) + NEG * fminf(e2, 0.f));
    float w3 = __expf(fmaxf(e3, 0.f) + NEG * fminf(e3, 0.f));
    float x0 = 0.f, x1 = 0.f, x2 = 0.f, x3 = 0.f;
    if (lane < NCLS) {
      x0 = bf2f(xw2b[(size_t)s0 * 40 + lane]);
      x1 = bf2f(xw2b[(size_t)s1 * 40 + lane]);
      x2 = bf2f(xw2b[(size_t)s2 * 40 + lane]);
      x3 = bf2f(xw2b[(size_t)s3 * 40 + lane]);
    }
    denom += (w0 + w1) + (w2 + w3);
    acc += w0 * x0 + w1 * x1 + w2 * x2 + w3 * x3;
  }
  for (; i < lim; ++i) {
    int s = col[i];
    float e = a2s[s] + ad;
    float w = __expf(fmaxf(e, 0.f) + NEG * fminf(e, 0.f));
    denom += w;
    if (lane < NCLS) acc += w * bf2f(xw2b[(size_t)s * 40 + lane]);
  }
  if (sub) {
    if (lane < NCLS) ps[nl][lane] = acc;
    if (lane == 0) pd[nl] = denom;
  }
  __syncthreads();
  if (!sub) {
    denom += pd[nl];
    if (lane < NCLS) {
      acc += ps[nl][lane];
      out[(size_t)node * 40 + lane] = acc / denom + b2[lane];
    }
  }
}

extern "C" void kernel_launch(void* const* d_in, const int* in_sizes, int n_in,
                              void* d_out, int out_size, void* d_ws, size_t ws_size,
                              hipStream_t stream) {
  const float* x     = (const float*)d_in[0];
  const int*   ei    = (const int*)d_in[1];
  const float* W1    = (const float*)d_in[2];
  const float* a1src = (const float*)d_in[3];
  const float* a1dst = (const float*)d_in[4];
  const float* b1    = (const float*)d_in[5];
  const float* W2    = (const float*)d_in[6];
  const float* a2src = (const float*)d_in[7];
  const float* a2dst = (const float*)d_in[8];
  const float* b2    = (const float*)d_in[9];
  float* out = (float*)d_out;

  const int* srcA = ei;
  const int* dstA = ei + NEDGES;

  // workspace layout
  ushort* w1t  = (ushort*)d_ws;                     // [320][256]
  ushort* w2t  = w1t + (size_t)320 * 256;           // [64][256]
  ushort* xw1b = w2t + (size_t)64 * 256;            // [NPAD][256]
  ushort* hb   = xw1b + (size_t)NPAD * 256;         // [NPAD][256]
  ushort* xw2b = hb + (size_t)NPAD * 256;           // [NPAD][40]
  float* a1s   = (float*)(xw2b + (size_t)NPAD * 40);
  float* a1d   = a1s + (size_t)NNODES * 8;
  float* a2s   = a1d + (size_t)NNODES * 8;          // NPAD
  float* a2d   = a2s + NPAD;                        // NPAD
  int* row_ptr = (int*)(a2d + NPAD);                // NNODES+1
  int* cnt     = row_ptr + (NNODES + 1);            // NNODES
  int* col     = cnt + NNODES;                      // ETOT
  int* bsum    = col + ETOT;                        // NSCB

  prep_k<<<628, 256, 0, stream>>>(W1, W2, a1src, a1dst, a2src, a2dst, w1t, w2t, cnt, hb);

  gemm1_mfma<<<NPAD / 64, 256, 0, stream>>>(x, w1t, xw1b, a1s, a1d);

  hist_k<<<(ETOT + 255) / 256, 256, 0, stream>>>(dstA, cnt);
  scan1_k<<<NSCB, SCAN_B, 0, stream>>>(cnt, row_ptr, bsum);
  scan2_k<<<1, 256, 0, stream>>>(bsum);
  scan3_k<<<NSCB, SCAN_B, 0, stream>>>(bsum, row_ptr);
  scatter_k<<<(ETOT + 255) / 256, 256, 0, stream>>>(srcA, dstA, row_ptr, cnt, col);

  agg1_k<<<NNODES / 2, 256, 0, stream>>>(xw1b, a1s, a1d, row_ptr, col, b1, hb);

  gemm2_mfma<<<NPAD / 64, 256, 0, stream>>>(hb, w2t, xw2b, a2s, a2d);

  agg2_k<<<NNODES / 2, 256, 0, stream>>>(xw2b, a2s, a2d, row_ptr, col, b2, out);
}